// Round 1
// baseline (687.308 us; speedup 1.0000x reference)
//
#include <hip/hip_runtime.h>
#include <hip/hip_bf16.h>

// ---------------------------------------------------------------------------
// CCAMemoryModel forward, f32 throughout.
// Pipeline:
//  k_compose : K1[tap][o] = sum_c w1b[o,c,dm]*w1a[c,db]  (block1 collapsed to one 4D conv)
//  k_proj    : channel-mean-shift + 1x1 conv + BN(eval) + ReLU + L2norm  (feat_b -> fbp, feat_m -> fmp)
//  k_cca     : per (b,n) block: corr GEMM in LDS -> 81-tap 4D conv (16ch, ReLU)
//              -> w2a base-conv reduce -> w2b mem-conv -> corr2 (global)
//  k_msoft   : gaussian-normalize over mem axis + softmax + sum over base -> attn_memory
//  k_attmem  : att_mem[b,n,c] = sum_m attn_memory * feat_m / 100
//  k_enc     : enc = spatial mean of feat_b, plus ||enc||
//  k_final   : cosine content weights + softmax over N + mem_vec + linear head
// ---------------------------------------------------------------------------

__global__ __launch_bounds__(256) void k_compose(const float* __restrict__ w1a,
                                                 const float* __restrict__ w1b,
                                                 float* __restrict__ K1g) {
    for (int i = threadIdx.x; i < 81 * 16; i += 256) {
        int o = i & 15, tap = i >> 4;
        int dm = tap / 9, db = tap % 9;
        float s = 0.f;
        for (int c = 0; c < 16; ++c)
            s += w1b[(o * 16 + c) * 9 + dm] * w1a[c * 9 + db];
        K1g[tap * 16 + o] = s;
    }
}

// 4 waves/block, each wave handles one (img, hw) position.
__global__ __launch_bounds__(256) void k_proj(const float* __restrict__ x,
                                              const float* __restrict__ w1x1,
                                              const float* __restrict__ gamma,
                                              const float* __restrict__ beta,
                                              float* __restrict__ out) {
    __shared__ __align__(16) float X[4][512];
    int wave = threadIdx.x >> 6, lane = threadIdx.x & 63;
    int pos = blockIdx.x * 4 + wave;
    int img = pos / 100, hw = pos % 100;
    const float* xp = x + (size_t)img * 51200 + hw;
    float* Xw = X[wave];
    float part = 0.f;
    for (int c = lane; c < 512; c += 64) {
        float v = xp[(size_t)c * 100];
        Xw[c] = v;
        part += v;
    }
#pragma unroll
    for (int o = 32; o; o >>= 1) part += __shfl_xor(part, o);
    float mean = part * (1.f / 512.f);
    __syncthreads();
    // y = sum_c (X[c]-mean)*w[r][c] = dot - mean*sum(w)
    float y = 0.f, wsum = 0.f;
    const float* wr = w1x1 + (size_t)lane * 512;
    for (int c = 0; c < 512; c += 4) {
        float4 xv = *(const float4*)&Xw[c];
        float4 wv = *(const float4*)&wr[c];
        y = fmaf(xv.x, wv.x, y); y = fmaf(xv.y, wv.y, y);
        y = fmaf(xv.z, wv.z, y); y = fmaf(xv.w, wv.w, y);
        wsum += wv.x + wv.y + wv.z + wv.w;
    }
    y -= mean * wsum;
    float z = fmaxf(y * gamma[lane] + beta[lane], 0.f);
    float ss = z * z;
#pragma unroll
    for (int o = 32; o; o >>= 1) ss += __shfl_xor(ss, o);
    float inv = 1.f / fmaxf(sqrtf(ss), 1e-8f);
    out[((size_t)img * 64 + lane) * 100 + hw] = z * inv;
}

// Main fused kernel: one block per (b,n) pair.
__global__ __launch_bounds__(256) void k_cca(const float* __restrict__ fbp,
                                             const float* __restrict__ fmp,
                                             const float* __restrict__ K1g,
                                             const float* __restrict__ w2a,
                                             const float* __restrict__ w2b,
                                             float* __restrict__ out2) {
    // corrT: [mem 101][bh 12][bw 16], slot 100 = zeros (mem-padding source),
    //        base dims zero-padded. 19392 f32.
    __shared__ __align__(16) float corrT[19392];
    __shared__ __align__(16) float hbuf[16000];  // h[16][10 wm][100 b]; staging overlay (12800) first
    __shared__ __align__(16) float g1r[3000];    // ring of 3 g1 rows [10 wm][100 b]
    int tid = threadIdx.x;
    int bn = blockIdx.x;
    int b_img = bn >> 6, n_img = bn & 63;

    // ---- stage fmp[n], fbp[b] + zero corrT ----
    const float* fm = fmp + (size_t)n_img * 6400;
    const float* fb = fbp + (size_t)b_img * 6400;
    for (int i = tid; i < 6400; i += 256) {
        hbuf[i] = fm[i];
        hbuf[6400 + i] = fb[i];
    }
    for (int i = tid; i < 19392; i += 256) corrT[i] = 0.f;
    __syncthreads();

    // ---- corr GEMM: corr[m][b] = sum_r fm[r][m]*fb[r][b], written padded ----
    for (int u = tid; u < 625; u += 256) {
        int m0 = (u / 25) * 4, b0 = (u % 25) * 4;
        float acc[4][4] = {};
        for (int r = 0; r < 64; ++r) {
            float4 av = *(const float4*)&hbuf[r * 100 + m0];
            float4 bv = *(const float4*)&hbuf[6400 + r * 100 + b0];
            float a[4] = {av.x, av.y, av.z, av.w};
            float bb[4] = {bv.x, bv.y, bv.z, bv.w};
#pragma unroll
            for (int i = 0; i < 4; ++i)
#pragma unroll
                for (int j = 0; j < 4; ++j) acc[i][j] = fmaf(a[i], bb[j], acc[i][j]);
        }
#pragma unroll
        for (int i = 0; i < 4; ++i) {
            int m = m0 + i;
#pragma unroll
            for (int j = 0; j < 4; ++j) {
                int bl = b0 + j, bh = bl / 10, bw = bl % 10;
                corrT[(m * 12 + bh + 1) * 16 + bw + 1] = acc[i][j];
            }
        }
    }
    __syncthreads();

    // ---- unit mapping for h/g1 passes: 200 units = (wm, bh, half) ----
    bool act = tid < 200;
    int wm = 0, bh = 0, bw0 = 0;
    if (act) { wm = tid / 20; bh = (tid / 2) % 10; bw0 = (tid & 1) * 5; }

    for (int mr = 0; mr < 10; ++mr) {
        // ---- h pass: 81-tap composed conv, 16 out channels, ReLU ----
        if (act) {
            float acc[16][5] = {};
#pragma unroll 1
            for (int dmh = 0; dmh < 3; ++dmh) {
                int mrow = mr + dmh - 1;
                if ((unsigned)mrow < 10u) {
#pragma unroll 1
                    for (int dmw = 0; dmw < 3; ++dmw) {
                        int mcol = wm + dmw - 1;
                        int mpos = ((unsigned)mcol < 10u) ? mrow * 10 + mcol : 100;
#pragma unroll 1
                        for (int dbh = 0; dbh < 3; ++dbh) {
                            const float* base = &corrT[(mpos * 12 + bh + dbh) * 16 + bw0];
                            float w[7];
#pragma unroll
                            for (int t = 0; t < 7; ++t) w[t] = base[t];
                            const float* kp = K1g + ((dmh * 3 + dmw) * 9 + dbh * 3) * 16;
#pragma unroll
                            for (int dbw = 0; dbw < 3; ++dbw) {
#pragma unroll
                                for (int c = 0; c < 16; ++c) {
                                    float k = kp[dbw * 16 + c];
#pragma unroll
                                    for (int j = 0; j < 5; ++j)
                                        acc[c][j] = fmaf(k, w[dbw + j], acc[c][j]);
                                }
                            }
                        }
                    }
                }
            }
#pragma unroll
            for (int c = 0; c < 16; ++c)
#pragma unroll
                for (int j = 0; j < 5; ++j)
                    hbuf[(c * 10 + wm) * 100 + bh * 10 + bw0 + j] = fmaxf(acc[c][j], 0.f);
        }
        __syncthreads();

        // ---- g1 pass: base conv 16->1 with w2a ----
        if (act) {
            float a5[5] = {};
#pragma unroll 1
            for (int c = 0; c < 16; ++c) {
                const float* hb = &hbuf[(c * 10 + wm) * 100];
#pragma unroll 1
                for (int dbh = 0; dbh < 3; ++dbh) {
                    int hrow = bh + dbh - 1;
                    bool rok = (unsigned)hrow < 10u;
                    float w[7];
#pragma unroll
                    for (int t = 0; t < 7; ++t) {
                        int col = bw0 - 1 + t;
                        bool ok = rok && ((unsigned)col < 10u);
                        int idx = ok ? hrow * 10 + col : 0;
                        float v = hb[idx];
                        w[t] = ok ? v : 0.f;
                    }
                    const float* wap = w2a + c * 9 + dbh * 3;
#pragma unroll
                    for (int dbw = 0; dbw < 3; ++dbw) {
                        float k = wap[dbw];
#pragma unroll
                        for (int j = 0; j < 5; ++j) a5[j] = fmaf(k, w[dbw + j], a5[j]);
                    }
                }
            }
            float* g1p = &g1r[(mr % 3) * 1000 + wm * 100 + bh * 10 + bw0];
#pragma unroll
            for (int j = 0; j < 5; ++j) g1p[j] = a5[j];
        }
        __syncthreads();

        // ---- g2 pass for output row ro = mr-1: mem conv 1->1 with w2b ----
        if (mr >= 1) {
            int ro = mr - 1;
            for (int p = tid; p < 1000; p += 256) {
                int wmo = p / 100, bo = p % 100;
                float s = 0.f;
#pragma unroll
                for (int dmh = 0; dmh < 3; ++dmh) {
                    int r2 = ro + dmh - 1;
                    if ((unsigned)r2 < 10u) {
#pragma unroll
                        for (int dmw = 0; dmw < 3; ++dmw) {
                            int wm2 = wmo + dmw - 1;
                            if ((unsigned)wm2 < 10u)
                                s = fmaf(w2b[dmh * 3 + dmw], g1r[(r2 % 3) * 1000 + wm2 * 100 + bo], s);
                        }
                    }
                }
                out2[(size_t)bn * 10000 + (ro * 10 + wmo) * 100 + bo] = s;
            }
        }
        __syncthreads();
    }
    // ---- final output row ro = 9 ----
    {
        int ro = 9;
        for (int p = tid; p < 1000; p += 256) {
            int wmo = p / 100, bo = p % 100;
            float s = 0.f;
#pragma unroll
            for (int dmh = 0; dmh < 3; ++dmh) {
                int r2 = ro + dmh - 1;
                if ((unsigned)r2 < 10u) {
#pragma unroll
                    for (int dmw = 0; dmw < 3; ++dmw) {
                        int wm2 = wmo + dmw - 1;
                        if ((unsigned)wm2 < 10u)
                            s = fmaf(w2b[dmh * 3 + dmw], g1r[(r2 % 3) * 1000 + wm2 * 100 + bo], s);
                    }
                }
            }
            out2[(size_t)bn * 10000 + (ro * 10 + wmo) * 100 + bo] = s;
        }
    }
}

// gaussian-normalize over mem axis (100), softmax over mem, sum over base.
__global__ __launch_bounds__(256) void k_msoft(const float* __restrict__ out2,
                                               float* __restrict__ attnm) {
    __shared__ float tile[10000];
    __shared__ float inv[100];
    int tid = threadIdx.x, bn = blockIdx.x;
    const float* src = out2 + (size_t)bn * 10000;
    for (int i = tid; i < 10000; i += 256) tile[i] = src[i];
    __syncthreads();
    if (tid < 100) {
        int b = tid;
        float s = 0.f, ss = 0.f;
        for (int m = 0; m < 100; ++m) {
            float v = tile[m * 100 + b];
            s += v; ss = fmaf(v, v, ss);
        }
        float mean = s * 0.01f;
        float var = (ss - 100.f * mean * mean) * (1.f / 99.f);
        float istd = 0.2f / sqrtf(var + 1e-5f);  // includes 1/TEMP
        float mx = -1e30f;
        for (int m = 0; m < 100; ++m)
            mx = fmaxf(mx, (tile[m * 100 + b] - mean) * istd);
        float se = 0.f;
        for (int m = 0; m < 100; ++m) {
            float e = expf((tile[m * 100 + b] - mean) * istd - mx);
            tile[m * 100 + b] = e;
            se += e;
        }
        inv[b] = 1.f / se;
    }
    __syncthreads();
    if (tid < 100) {
        int m = tid;
        float s = 0.f;
        for (int b = 0; b < 100; ++b) s = fmaf(tile[m * 100 + b], inv[b], s);
        attnm[bn * 100 + m] = s;
    }
}

__global__ __launch_bounds__(256) void k_attmem(const float* __restrict__ attnm,
                                                const float* __restrict__ feat_m,
                                                float* __restrict__ attm) {
    __shared__ float A[8][100];
    int n = blockIdx.x, tid = threadIdx.x;
    for (int i = tid; i < 800; i += 256) {
        int b = i / 100, m = i % 100;
        A[b][m] = attnm[(b * 64 + n) * 100 + m];
    }
    __syncthreads();
    for (int c = tid; c < 512; c += 256) {
        const float* fp = feat_m + ((size_t)n * 512 + c) * 100;
        float acc[8] = {};
        for (int m4 = 0; m4 < 100; m4 += 4) {
            float4 v = *(const float4*)&fp[m4];
#pragma unroll
            for (int b = 0; b < 8; ++b) {
                acc[b] = fmaf(A[b][m4], v.x, acc[b]);
                acc[b] = fmaf(A[b][m4 + 1], v.y, acc[b]);
                acc[b] = fmaf(A[b][m4 + 2], v.z, acc[b]);
                acc[b] = fmaf(A[b][m4 + 3], v.w, acc[b]);
            }
        }
#pragma unroll
        for (int b = 0; b < 8; ++b)
            attm[((size_t)(b * 64 + n)) * 512 + c] = acc[b] * 0.01f;
    }
}

__global__ __launch_bounds__(512) void k_enc(const float* __restrict__ feat_b,
                                             float* __restrict__ enc,
                                             float* __restrict__ encn) {
    __shared__ float red[512];
    int b = blockIdx.x, c = threadIdx.x;
    const float* fp = feat_b + ((size_t)b * 512 + c) * 100;
    float s = 0.f;
    for (int m = 0; m < 100; m += 4) {
        float4 v = *(const float4*)&fp[m];
        s += v.x + v.y + v.z + v.w;
    }
    float e = s * 0.01f;
    enc[b * 512 + c] = e;
    red[c] = e * e;
    __syncthreads();
    for (int o = 256; o; o >>= 1) {
        if (c < o) red[c] += red[c + o];
        __syncthreads();
    }
    if (c == 0) encn[b] = sqrtf(red[0]);
}

__global__ __launch_bounds__(256) void k_final(const float* __restrict__ attm,
                                               const float* __restrict__ enc,
                                               const float* __restrict__ encn,
                                               const float* __restrict__ w_fc,
                                               const float* __restrict__ b_fc,
                                               float* __restrict__ out) {
    __shared__ float attL[64 * 513];
    __shared__ float encL[512];
    __shared__ float mv[512];
    __shared__ float wL[64];
    int b = blockIdx.x, tid = threadIdx.x;
    const float* ap = attm + (size_t)b * 32768;
    for (int i = tid; i < 32768; i += 256) attL[(i >> 9) * 513 + (i & 511)] = ap[i];
    for (int i = tid; i < 512; i += 256) encL[i] = enc[b * 512 + i];
    __syncthreads();
    float escale = 1.f / fmaxf(encn[b], 1e-8f);
    if (tid < 64) {
        int n = tid;
        float ss = 0.f, dp = 0.f;
        for (int c = 0; c < 512; ++c) {
            float a = attL[n * 513 + c];
            ss = fmaf(a, a, ss);
            dp = fmaf(encL[c], a, dp);
        }
        float sc = dp * escale / fmaxf(sqrtf(ss), 1e-8f);
        float mx = sc;
#pragma unroll
        for (int o = 32; o; o >>= 1) mx = fmaxf(mx, __shfl_xor(mx, o));
        float e = expf(sc - mx);
        float se = e;
#pragma unroll
        for (int o = 32; o; o >>= 1) se += __shfl_xor(se, o);
        wL[n] = e / se;
    }
    __syncthreads();
    for (int c = tid; c < 512; c += 256) {
        float s = 0.f;
        for (int n = 0; n < 64; ++n) s = fmaf(wL[n], attL[n * 513 + c], s);
        mv[c] = s;
    }
    __syncthreads();
    for (int k = tid; k < 100; k += 256) {
        const float* wp = w_fc + (size_t)k * 1024;
        float acc = b_fc[k];
        for (int c = 0; c < 512; c += 4) {
            float4 w0 = *(const float4*)&wp[c];
            float4 w1 = *(const float4*)&wp[512 + c];
            acc = fmaf(encL[c], w0.x, acc);     acc = fmaf(encL[c + 1], w0.y, acc);
            acc = fmaf(encL[c + 2], w0.z, acc); acc = fmaf(encL[c + 3], w0.w, acc);
            acc = fmaf(mv[c], w1.x, acc);       acc = fmaf(mv[c + 1], w1.y, acc);
            acc = fmaf(mv[c + 2], w1.z, acc);   acc = fmaf(mv[c + 3], w1.w, acc);
        }
        out[b * 100 + k] = acc;
    }
}

extern "C" void kernel_launch(void* const* d_in, const int* in_sizes, int n_in,
                              void* d_out, int out_size, void* d_ws, size_t ws_size,
                              hipStream_t stream) {
    const float* feat_b = (const float*)d_in[0];
    const float* feat_m = (const float*)d_in[1];
    const float* w1x1   = (const float*)d_in[2];
    const float* gamma  = (const float*)d_in[3];
    const float* beta   = (const float*)d_in[4];
    const float* w1a    = (const float*)d_in[5];
    const float* w1b    = (const float*)d_in[6];
    const float* w2a    = (const float*)d_in[7];
    const float* w2b    = (const float*)d_in[8];
    const float* w_fc   = (const float*)d_in[9];
    const float* b_fc   = (const float*)d_in[10];

    float* ws    = (float*)d_ws;
    float* K1g   = ws;                    // 1296 (pad 1312)
    float* fbp   = ws + 1312;             // 8*64*100   = 51200
    float* fmp   = fbp + 51200;           // 64*64*100  = 409600
    float* out2  = fmp + 409600;          // 512*10000  = 5120000
    float* attnm = out2 + 5120000;        // 512*100    = 51200
    float* attm  = attnm + 51200;         // 8*64*512   = 262144
    float* enc   = attm + 262144;         // 8*512      = 4096
    float* encn  = enc + 4096;            // 8

    hipLaunchKernelGGL(k_compose, dim3(1), dim3(256), 0, stream, w1a, w1b, K1g);
    hipLaunchKernelGGL(k_proj, dim3(200), dim3(256), 0, stream, feat_b, w1x1, gamma, beta, fbp);
    hipLaunchKernelGGL(k_proj, dim3(1600), dim3(256), 0, stream, feat_m, w1x1, gamma, beta, fmp);
    hipLaunchKernelGGL(k_cca, dim3(512), dim3(256), 0, stream, fbp, fmp, K1g, w2a, w2b, out2);
    hipLaunchKernelGGL(k_msoft, dim3(512), dim3(256), 0, stream, out2, attnm);
    hipLaunchKernelGGL(k_attmem, dim3(64), dim3(256), 0, stream, attnm, feat_m, attm);
    hipLaunchKernelGGL(k_enc, dim3(8), dim3(512), 0, stream, feat_b, enc, encn);
    hipLaunchKernelGGL(k_final, dim3(8), dim3(256), 0, stream, attm, enc, encn, w_fc, b_fc, (float*)d_out);
}

// Round 2
// 446.305 us; speedup vs baseline: 1.5400x; 1.5400x over previous
//
#include <hip/hip_runtime.h>
#include <hip/hip_bf16.h>

// ---------------------------------------------------------------------------
// CCAMemoryModel forward, f32 throughout.
//  k_compose : K1[tap][o] = sum_c w1b[o,c,dm]*w1a[c,db]  (block1 collapsed)
//  k_proj    : mean-shift + 1x1 conv + BN + ReLU + L2norm
//  k_cca     : per (b,n): corr GEMM in LDS -> composed 81-tap conv (16ch,ReLU)
//              -> w2a base-conv -> w2b mem-conv -> out2
//              512 thr, 500 units (wm,bh,bw-pair); odd LDS strides (13/101)
//              to kill bank conflicts; K weights via uniform s_load.
//  k_msoft   : gaussian-normalize + softmax over mem + sum over base
//  k_attmem  : att_mem[b,n,c]
//  k_enc     : enc + ||enc||
//  k_final   : cosine weights + softmax + mem_vec + linear head
// ---------------------------------------------------------------------------

__global__ __launch_bounds__(256) void k_compose(const float* __restrict__ w1a,
                                                 const float* __restrict__ w1b,
                                                 float* __restrict__ K1g) {
    for (int i = threadIdx.x; i < 81 * 16; i += 256) {
        int o = i & 15, tap = i >> 4;
        int dm = tap / 9, db = tap % 9;
        float s = 0.f;
        for (int c = 0; c < 16; ++c)
            s += w1b[(o * 16 + c) * 9 + dm] * w1a[c * 9 + db];
        K1g[tap * 16 + o] = s;
    }
}

__global__ __launch_bounds__(256) void k_proj(const float* __restrict__ x,
                                              const float* __restrict__ w1x1,
                                              const float* __restrict__ gamma,
                                              const float* __restrict__ beta,
                                              float* __restrict__ out) {
    __shared__ __align__(16) float X[4][512];
    int wave = threadIdx.x >> 6, lane = threadIdx.x & 63;
    int pos = blockIdx.x * 4 + wave;
    int img = pos / 100, hw = pos % 100;
    const float* xp = x + (size_t)img * 51200 + hw;
    float* Xw = X[wave];
    float part = 0.f;
    for (int c = lane; c < 512; c += 64) {
        float v = xp[(size_t)c * 100];
        Xw[c] = v;
        part += v;
    }
#pragma unroll
    for (int o = 32; o; o >>= 1) part += __shfl_xor(part, o);
    float mean = part * (1.f / 512.f);
    __syncthreads();
    float y = 0.f, wsum = 0.f;
    const float* wr = w1x1 + (size_t)lane * 512;
    for (int c = 0; c < 512; c += 4) {
        float4 xv = *(const float4*)&Xw[c];
        float4 wv = *(const float4*)&wr[c];
        y = fmaf(xv.x, wv.x, y); y = fmaf(xv.y, wv.y, y);
        y = fmaf(xv.z, wv.z, y); y = fmaf(xv.w, wv.w, y);
        wsum += wv.x + wv.y + wv.z + wv.w;
    }
    y -= mean * wsum;
    float z = fmaxf(y * gamma[lane] + beta[lane], 0.f);
    float ss = z * z;
#pragma unroll
    for (int o = 32; o; o >>= 1) ss += __shfl_xor(ss, o);
    float inv = 1.f / fmaxf(sqrtf(ss), 1e-8f);
    out[((size_t)img * 64 + lane) * 100 + hw] = z * inv;
}

// corrT: [101 mpos][12 rows][13 cols] (row stride 13, mpos stride 156); slot
// 100 = zeros. h: [(c*10+wm)*101 + bh*10+bw]. g1 ring: 3 slabs of 1010.
__global__ __launch_bounds__(512, 2) void k_cca(const float* __restrict__ fbp,
                                                const float* __restrict__ fmp,
                                                const float* __restrict__ K1g,
                                                const float* __restrict__ w2a,
                                                const float* __restrict__ w2b,
                                                float* __restrict__ out2) {
    __shared__ __align__(16) float corrT[15756];
    __shared__ __align__(16) float hbuf[16160];
    __shared__ __align__(16) float g1r[3030];
    const int tid = threadIdx.x;
    const int bn = blockIdx.x;
    const int b_img = bn >> 6, n_img = bn & 63;

    // ---- stage fmp[n], fbp[b] (overlay in hbuf) + zero corrT ----
    const float* fm = fmp + (size_t)n_img * 6400;
    const float* fb = fbp + (size_t)b_img * 6400;
    for (int i = tid; i < 6400; i += 512) {
        hbuf[i] = fm[i];
        hbuf[6400 + i] = fb[i];
    }
    for (int i = tid; i < 15756; i += 512) corrT[i] = 0.f;
    __syncthreads();

    // ---- corr GEMM: corr[m][b] = sum_r fm[r][m]*fb[r][b] ----
    for (int u = tid; u < 625; u += 512) {
        int m0 = (u / 25) * 4, b0 = (u % 25) * 4;
        float acc[4][4] = {};
        for (int r = 0; r < 64; ++r) {
            float4 av = *(const float4*)&hbuf[r * 100 + m0];
            float4 bv = *(const float4*)&hbuf[6400 + r * 100 + b0];
            float a[4] = {av.x, av.y, av.z, av.w};
            float bb[4] = {bv.x, bv.y, bv.z, bv.w};
#pragma unroll
            for (int i = 0; i < 4; ++i)
#pragma unroll
                for (int j = 0; j < 4; ++j) acc[i][j] = fmaf(a[i], bb[j], acc[i][j]);
        }
#pragma unroll
        for (int i = 0; i < 4; ++i) {
            int m = m0 + i;
#pragma unroll
            for (int j = 0; j < 4; ++j) {
                int bl = b0 + j, bh = bl / 10, bw = bl % 10;
                corrT[m * 156 + (bh + 1) * 13 + (bw + 1)] = acc[i][j];
            }
        }
    }
    __syncthreads();

    // ---- 500 units: (wm, bh, bw-pair) ----
    const bool act = tid < 500;
    int wm = 0, bh = 0, bw0 = 0;
    if (act) { wm = tid / 50; int r = tid % 50; bh = r / 5; bw0 = (r % 5) * 2; }

    for (int mr = 0; mr < 10; ++mr) {
        // ---- h pass: composed 81-tap conv, 16 channels, ReLU ----
        if (act) {
            float a0[16] = {}, a1[16] = {};
            for (int dmh = 0; dmh < 3; ++dmh) {
                int mrow = mr + dmh - 1;
                if ((unsigned)mrow < 10u) {
                    for (int dmw = 0; dmw < 3; ++dmw) {
                        int mcol = wm + dmw - 1;
                        int mpos = ((unsigned)mcol < 10u) ? mrow * 10 + mcol : 100;
                        const float* cb = &corrT[mpos * 156 + bh * 13 + bw0];
                        const float* kb = K1g + (dmh * 3 + dmw) * 144;  // 9*16
#pragma unroll
                        for (int dbh = 0; dbh < 3; ++dbh) {
                            float w0 = cb[dbh * 13 + 0], w1 = cb[dbh * 13 + 1];
                            float w2 = cb[dbh * 13 + 2], w3 = cb[dbh * 13 + 3];
                            const float* kp = kb + dbh * 48;
#pragma unroll
                            for (int c = 0; c < 16; ++c) {
                                float k0 = kp[c], k1 = kp[16 + c], k2 = kp[32 + c];
                                a0[c] = fmaf(k0, w0, fmaf(k1, w1, fmaf(k2, w2, a0[c])));
                                a1[c] = fmaf(k0, w1, fmaf(k1, w2, fmaf(k2, w3, a1[c])));
                            }
                        }
                    }
                }
            }
#pragma unroll
            for (int c = 0; c < 16; ++c) {
                float* hp = &hbuf[(c * 10 + wm) * 101 + bh * 10 + bw0];
                hp[0] = fmaxf(a0[c], 0.f);
                hp[1] = fmaxf(a1[c], 0.f);
            }
        }
        __syncthreads();

        // ---- g1 pass: base conv 16->1 with w2a ----
        if (act) {
            float a0 = 0.f, a1 = 0.f;
#pragma unroll
            for (int c = 0; c < 16; ++c) {
                const float* hb = &hbuf[(c * 10 + wm) * 101];
                const float* wap = w2a + c * 9;
#pragma unroll
                for (int dbh = 0; dbh < 3; ++dbh) {
                    int hrow = bh + dbh - 1;
                    bool rok = (unsigned)hrow < 10u;
                    float w[4];
#pragma unroll
                    for (int t = 0; t < 4; ++t) {
                        int col = bw0 - 1 + t;
                        bool ok = rok && ((unsigned)col < 10u);
                        float v = hb[ok ? hrow * 10 + col : 0];
                        w[t] = ok ? v : 0.f;
                    }
                    float k0 = wap[dbh * 3 + 0], k1 = wap[dbh * 3 + 1], k2 = wap[dbh * 3 + 2];
                    a0 = fmaf(k0, w[0], fmaf(k1, w[1], fmaf(k2, w[2], a0)));
                    a1 = fmaf(k0, w[1], fmaf(k1, w[2], fmaf(k2, w[3], a1)));
                }
            }
            float* gp = &g1r[(mr % 3) * 1010 + wm * 101 + bh * 10 + bw0];
            gp[0] = a0;
            gp[1] = a1;
        }
        __syncthreads();

        // ---- g2: mem conv 1->1 with w2b for output row ro = mr-1 ----
        if (mr >= 1) {
            int ro = mr - 1;
            for (int p = tid; p < 1000; p += 512) {
                int wmo = p / 100, bo = p % 100;
                float s = 0.f;
#pragma unroll
                for (int dmh = 0; dmh < 3; ++dmh) {
                    int r2 = ro + dmh - 1;
                    if ((unsigned)r2 < 10u) {
#pragma unroll
                        for (int dmw = 0; dmw < 3; ++dmw) {
                            int wm2 = wmo + dmw - 1;
                            if ((unsigned)wm2 < 10u)
                                s = fmaf(w2b[dmh * 3 + dmw],
                                         g1r[(r2 % 3) * 1010 + wm2 * 101 + bo], s);
                        }
                    }
                }
                out2[(size_t)bn * 10000 + (ro * 10 + wmo) * 100 + bo] = s;
            }
        }
        __syncthreads();
    }
    {
        int ro = 9;
        for (int p = tid; p < 1000; p += 512) {
            int wmo = p / 100, bo = p % 100;
            float s = 0.f;
#pragma unroll
            for (int dmh = 0; dmh < 3; ++dmh) {
                int r2 = ro + dmh - 1;
                if ((unsigned)r2 < 10u) {
#pragma unroll
                    for (int dmw = 0; dmw < 3; ++dmw) {
                        int wm2 = wmo + dmw - 1;
                        if ((unsigned)wm2 < 10u)
                            s = fmaf(w2b[dmh * 3 + dmw],
                                     g1r[(r2 % 3) * 1010 + wm2 * 101 + bo], s);
                    }
                }
            }
            out2[(size_t)bn * 10000 + (ro * 10 + wmo) * 100 + bo] = s;
        }
    }
}

// gaussian-normalize over mem axis + softmax + sum over base.
// 2 threads per base-column (halves combined via shfl_xor(1)).
__global__ __launch_bounds__(256) void k_msoft(const float* __restrict__ out2,
                                               float* __restrict__ attnm) {
    __shared__ float tile[10000];
    __shared__ float invS[100];
    int tid = threadIdx.x, bn = blockIdx.x;
    const float* src = out2 + (size_t)bn * 10000;
    for (int i = tid; i < 10000; i += 256) tile[i] = src[i];
    __syncthreads();
    if (tid < 200) {
        int b = tid >> 1, h = tid & 1;
        int m0 = h * 50;
        float s = 0.f, ss = 0.f;
        for (int i = 0; i < 50; ++i) {
            float v = tile[(m0 + i) * 100 + b];
            s += v; ss = fmaf(v, v, ss);
        }
        s += __shfl_xor(s, 1);
        ss += __shfl_xor(ss, 1);
        float mean = s * 0.01f;
        float var = (ss - 100.f * mean * mean) * (1.f / 99.f);
        float istd = 0.2f / sqrtf(var + 1e-5f);  // includes 1/TEMP
        float mx = -1e30f;
        for (int i = 0; i < 50; ++i)
            mx = fmaxf(mx, (tile[(m0 + i) * 100 + b] - mean) * istd);
        mx = fmaxf(mx, __shfl_xor(mx, 1));
        float se = 0.f;
        for (int i = 0; i < 50; ++i) {
            float e = expf((tile[(m0 + i) * 100 + b] - mean) * istd - mx);
            tile[(m0 + i) * 100 + b] = e;
            se += e;
        }
        se += __shfl_xor(se, 1);
        if (h == 0) invS[b] = 1.f / se;
    }
    __syncthreads();
    if (tid < 200) {
        int m = tid >> 1, h = tid & 1;
        float s = 0.f;
        for (int i = 0; i < 50; ++i) {
            int b = h * 50 + i;
            s = fmaf(tile[m * 100 + b], invS[b], s);
        }
        s += __shfl_xor(s, 1);
        if (h == 0) attnm[bn * 100 + m] = s;
    }
}

// grid (64 n, 4 c-chunks), block 128: one c per thread.
__global__ __launch_bounds__(128) void k_attmem(const float* __restrict__ attnm,
                                                const float* __restrict__ feat_m,
                                                float* __restrict__ attm) {
    __shared__ float A[8][100];
    int n = blockIdx.x, cq = blockIdx.y, tid = threadIdx.x;
    for (int i = tid; i < 800; i += 128) {
        int b = i / 100, m = i % 100;
        A[b][m] = attnm[(b * 64 + n) * 100 + m];
    }
    __syncthreads();
    int c = cq * 128 + tid;
    const float* fp = feat_m + ((size_t)n * 512 + c) * 100;
    float acc[8] = {};
    for (int m4 = 0; m4 < 100; m4 += 4) {
        float4 v = *(const float4*)&fp[m4];
#pragma unroll
        for (int b = 0; b < 8; ++b) {
            acc[b] = fmaf(A[b][m4], v.x, acc[b]);
            acc[b] = fmaf(A[b][m4 + 1], v.y, acc[b]);
            acc[b] = fmaf(A[b][m4 + 2], v.z, acc[b]);
            acc[b] = fmaf(A[b][m4 + 3], v.w, acc[b]);
        }
    }
#pragma unroll
    for (int b = 0; b < 8; ++b)
        attm[((size_t)(b * 64 + n)) * 512 + c] = acc[b] * 0.01f;
}

__global__ __launch_bounds__(512) void k_enc(const float* __restrict__ feat_b,
                                             float* __restrict__ enc,
                                             float* __restrict__ encn) {
    __shared__ float red[512];
    int b = blockIdx.x, c = threadIdx.x;
    const float* fp = feat_b + ((size_t)b * 512 + c) * 100;
    float s = 0.f;
    for (int m = 0; m < 100; m += 4) {
        float4 v = *(const float4*)&fp[m];
        s += v.x + v.y + v.z + v.w;
    }
    float e = s * 0.01f;
    enc[b * 512 + c] = e;
    red[c] = e * e;
    __syncthreads();
    for (int o = 256; o; o >>= 1) {
        if (c < o) red[c] += red[c + o];
        __syncthreads();
    }
    if (c == 0) encn[b] = sqrtf(red[0]);
}

__global__ __launch_bounds__(256) void k_final(const float* __restrict__ attm,
                                               const float* __restrict__ enc,
                                               const float* __restrict__ encn,
                                               const float* __restrict__ w_fc,
                                               const float* __restrict__ b_fc,
                                               float* __restrict__ out) {
    __shared__ float attL[64 * 513];
    __shared__ float encL[512];
    __shared__ float mv[512];
    __shared__ float wL[64];
    int b = blockIdx.x, tid = threadIdx.x;
    const float* ap = attm + (size_t)b * 32768;
    for (int i = tid; i < 32768; i += 256) attL[(i >> 9) * 513 + (i & 511)] = ap[i];
    for (int i = tid; i < 512; i += 256) encL[i] = enc[b * 512 + i];
    __syncthreads();
    float escale = 1.f / fmaxf(encn[b], 1e-8f);
    if (tid < 64) {
        int n = tid;
        float ss = 0.f, dp = 0.f;
        for (int c = 0; c < 512; ++c) {
            float a = attL[n * 513 + c];
            ss = fmaf(a, a, ss);
            dp = fmaf(encL[c], a, dp);
        }
        float sc = dp * escale / fmaxf(sqrtf(ss), 1e-8f);
        float mx = sc;
#pragma unroll
        for (int o = 32; o; o >>= 1) mx = fmaxf(mx, __shfl_xor(mx, o));
        float e = expf(sc - mx);
        float se = e;
#pragma unroll
        for (int o = 32; o; o >>= 1) se += __shfl_xor(se, o);
        wL[n] = e / se;
    }
    __syncthreads();
    for (int c = tid; c < 512; c += 256) {
        float s = 0.f;
        for (int n = 0; n < 64; ++n) s = fmaf(wL[n], attL[n * 513 + c], s);
        mv[c] = s;
    }
    __syncthreads();
    for (int k = tid; k < 100; k += 256) {
        const float* wp = w_fc + (size_t)k * 1024;
        float acc = b_fc[k];
        for (int c = 0; c < 512; c += 4) {
            float4 w0 = *(const float4*)&wp[c];
            float4 w1 = *(const float4*)&wp[512 + c];
            acc = fmaf(encL[c], w0.x, acc);     acc = fmaf(encL[c + 1], w0.y, acc);
            acc = fmaf(encL[c + 2], w0.z, acc); acc = fmaf(encL[c + 3], w0.w, acc);
            acc = fmaf(mv[c], w1.x, acc);       acc = fmaf(mv[c + 1], w1.y, acc);
            acc = fmaf(mv[c + 2], w1.z, acc);   acc = fmaf(mv[c + 3], w1.w, acc);
        }
        out[b * 100 + k] = acc;
    }
}

extern "C" void kernel_launch(void* const* d_in, const int* in_sizes, int n_in,
                              void* d_out, int out_size, void* d_ws, size_t ws_size,
                              hipStream_t stream) {
    const float* feat_b = (const float*)d_in[0];
    const float* feat_m = (const float*)d_in[1];
    const float* w1x1   = (const float*)d_in[2];
    const float* gamma  = (const float*)d_in[3];
    const float* beta   = (const float*)d_in[4];
    const float* w1a    = (const float*)d_in[5];
    const float* w1b    = (const float*)d_in[6];
    const float* w2a    = (const float*)d_in[7];
    const float* w2b    = (const float*)d_in[8];
    const float* w_fc   = (const float*)d_in[9];
    const float* b_fc   = (const float*)d_in[10];

    float* ws    = (float*)d_ws;
    float* K1g   = ws;                    // 1296 (pad 1312)
    float* fbp   = ws + 1312;             // 51200
    float* fmp   = fbp + 51200;           // 409600
    float* out2  = fmp + 409600;          // 5120000
    float* attnm = out2 + 5120000;        // 51200
    float* attm  = attnm + 51200;         // 262144
    float* enc   = attm + 262144;         // 4096
    float* encn  = enc + 4096;            // 8

    hipLaunchKernelGGL(k_compose, dim3(1), dim3(256), 0, stream, w1a, w1b, K1g);
    hipLaunchKernelGGL(k_proj, dim3(200), dim3(256), 0, stream, feat_b, w1x1, gamma, beta, fbp);
    hipLaunchKernelGGL(k_proj, dim3(1600), dim3(256), 0, stream, feat_m, w1x1, gamma, beta, fmp);
    hipLaunchKernelGGL(k_cca, dim3(512), dim3(512), 0, stream, fbp, fmp, K1g, w2a, w2b, out2);
    hipLaunchKernelGGL(k_msoft, dim3(512), dim3(256), 0, stream, out2, attnm);
    hipLaunchKernelGGL(k_attmem, dim3(64, 4), dim3(128), 0, stream, attnm, feat_m, attm);
    hipLaunchKernelGGL(k_enc, dim3(8), dim3(512), 0, stream, feat_b, enc, encn);
    hipLaunchKernelGGL(k_final, dim3(8), dim3(256), 0, stream, attm, enc, encn, w_fc, b_fc, (float*)d_out);
}

// Round 3
// 442.392 us; speedup vs baseline: 1.5536x; 1.0088x over previous
//
#include <hip/hip_runtime.h>
#include <hip/hip_bf16.h>

// ---------------------------------------------------------------------------
// CCAMemoryModel forward, f32 throughout.
//  k_compose : K1[tap][o] = sum_c w1b[o,c,dm]*w1a[c,db]  (block1 collapsed)
//  k_proj2   : per-image tiled GEMM proj (mean-shift+BN+ReLU+L2norm), coalesced
//  k_cca     : per (b,n): row-streamed corr (3-slot ring) -> composed 81-tap
//              conv in 2 channel-groups of 8 -> g1 (regs) -> g2 -> out2
//              LDS 69.4KB -> 2 blocks/CU.
//  k_msoft   : gaussian-normalize + softmax over mem + sum over base
//  k_attmem  : att_mem[b,n,c]
//  k_enc     : enc + ||enc||
//  k_final   : cosine weights + softmax + mem_vec + linear head
// ---------------------------------------------------------------------------

__global__ __launch_bounds__(256) void k_compose(const float* __restrict__ w1a,
                                                 const float* __restrict__ w1b,
                                                 float* __restrict__ K1g) {
    for (int i = threadIdx.x; i < 81 * 16; i += 256) {
        int o = i & 15, tap = i >> 4;
        int dm = tap / 9, db = tap % 9;
        float s = 0.f;
        for (int c = 0; c < 16; ++c)
            s += w1b[(o * 16 + c) * 9 + dm] * w1a[c * 9 + db];
        K1g[tap * 16 + o] = s;
    }
}

// One block per image (72 total: 8 feat_b + 64 feat_m).
__global__ __launch_bounds__(512) void k_proj2(const float* __restrict__ feat_b,
                                               const float* __restrict__ feat_m,
                                               const float* __restrict__ w1x1,
                                               const float* __restrict__ gamma,
                                               const float* __restrict__ beta,
                                               float* __restrict__ fbp,
                                               float* __restrict__ fmp) {
    __shared__ __align__(16) float xt[64][104];   // c-tile of x; reused as zbuf
    __shared__ __align__(16) float wt[64][68];    // c-tile of w1x1
    __shared__ float colsum[100];
    __shared__ float wsumL[64];
    __shared__ float invL[100];
    const int tid = threadIdx.x;
    const int img = blockIdx.x;
    const float* x;
    float* outp;
    if (img < 8) { x = feat_b + (size_t)img * 51200; outp = fbp + (size_t)img * 6400; }
    else         { x = feat_m + (size_t)(img - 8) * 51200; outp = fmp + (size_t)(img - 8) * 6400; }

    if (tid < 100) colsum[tid] = 0.f;
    if (tid < 64) wsumL[tid] = 0.f;
    const int r = tid >> 3, q = tid & 7;   // r: out-channel, q: hw-strip
    float acc[13];
#pragma unroll
    for (int j = 0; j < 13; ++j) acc[j] = 0.f;
    __syncthreads();

    for (int ct = 0; ct < 8; ++ct) {
        for (int i = tid; i < 1600; i += 512) {   // xt: 64x100 floats
            int row = i / 25, c4 = (i % 25) * 4;
            *(float4*)&xt[row][c4] = *(const float4*)&x[(size_t)(ct * 64 + row) * 100 + c4];
        }
        for (int i = tid; i < 1024; i += 512) {   // wt: 64x64 floats
            int row = i / 16, c4 = (i % 16) * 4;
            *(float4*)&wt[row][c4] = *(const float4*)&w1x1[(size_t)row * 512 + ct * 64 + c4];
        }
        __syncthreads();
        if (tid < 100) {
            float s = 0.f;
            for (int c = 0; c < 64; ++c) s += xt[c][tid];
            colsum[tid] += s;
        }
        if (tid < 64) {
            float s = 0.f;
            for (int c = 0; c < 64; ++c) s += wt[tid][c];
            wsumL[tid] += s;
        }
        for (int c = 0; c < 64; ++c) {
            float w = wt[r][c];
#pragma unroll
            for (int j = 0; j < 13; ++j) {
                int hw = q + 8 * j;
                if (hw < 100) acc[j] = fmaf(w, xt[c][hw], acc[j]);
            }
        }
        __syncthreads();
    }
    // z = relu((y - mean*wsum)*gamma + beta) into zbuf (= xt)
    float g = gamma[r], be = beta[r], wsr = wsumL[r];
#pragma unroll
    for (int j = 0; j < 13; ++j) {
        int hw = q + 8 * j;
        if (hw < 100) {
            float mean = colsum[hw] * (1.f / 512.f);
            xt[r][hw] = fmaxf((acc[j] - mean * wsr) * g + be, 0.f);
        }
    }
    __syncthreads();
    if (tid < 100) {
        float ss = 0.f;
        for (int rr = 0; rr < 64; ++rr) { float z = xt[rr][tid]; ss = fmaf(z, z, ss); }
        invL[tid] = 1.f / fmaxf(sqrtf(ss), 1e-8f);
    }
    __syncthreads();
    for (int i = tid; i < 6400; i += 512) {
        int rr = i / 100, hw = i % 100;
        outp[i] = xt[rr][hw] * invL[hw];
    }
}

// Main conv kernel. ring: 3 slots x [10 mcol][12][13] + zero row (156).
// hbuf: [8 c][10 wm][111] (stride 11 rows). g1r: 3 slots x [12 wm][101].
__global__ __launch_bounds__(512, 4) void k_cca(const float* __restrict__ fbp,
                                                const float* __restrict__ fmp,
                                                const float* __restrict__ K1g,
                                                const float* __restrict__ w2a,
                                                const float* __restrict__ w2b,
                                                float* __restrict__ out2) {
    __shared__ __align__(16) float ring[3 * 1560 + 156];  // 4836
    __shared__ __align__(16) float hbuf[8 * 10 * 111];    // 8880
    __shared__ __align__(16) float g1r[3 * 1212];         // 3636
    const int tid = threadIdx.x;
    const int bn = blockIdx.x;
    const int b_img = bn >> 6, n_img = bn & 63;
    const float* fb = fbp + (size_t)b_img * 6400;
    const float* fm = fmp + (size_t)n_img * 6400;

    // ---- init: zero-row of ring, g1 boundary rows (wm=-1, wm=10) ----
    for (int i = tid; i < 156; i += 512) ring[3 * 1560 + i] = 0.f;
    for (int i = tid; i < 606; i += 512) {
        int s = i / 202, t = i % 202;
        int row = (t < 101) ? 0 : 11;
        g1r[s * 1212 + row * 101 + (t % 101)] = 0.f;
    }

    // GEMM for one corr mem-row into ring slot mrow%3.
    // unit: mcol = tid%10, pair = tid/10 -> base b0=2*pair, b0+1.
    auto gemm_row = [&](int mrow) {
        if (tid < 500 && mrow < 10) {
            int mcol = tid % 10, pp = tid / 10, b0 = pp * 2;
            const float* fmr = fm + (mrow * 10 + mcol);
            const float* fbr = fb + b0;
            float a0 = 0.f, a1 = 0.f;
            for (int rr = 0; rr < 64; ++rr) {
                float mv = fmr[rr * 100];
                float2 bv = *(const float2*)&fbr[rr * 100];
                a0 = fmaf(mv, bv.x, a0);
                a1 = fmaf(mv, bv.y, a1);
            }
            int bh = b0 / 10, bw = b0 % 10;
            float* w = &ring[(mrow % 3) * 1560 + mcol * 156 + (bh + 1) * 13 + (bw + 1)];
            w[0] = a0; w[1] = a1;
        }
    };

    gemm_row(0);
    __syncthreads();

    const bool act = tid < 500;
    int wm = 0, bh = 0, bw0 = 0;
    if (act) { wm = tid / 50; int rr = tid % 50; bh = rr / 5; bw0 = (rr % 5) * 2; }

    for (int mr = 0; mr < 10; ++mr) {
        gemm_row(mr + 1);   // slot (mr+1)%3 previously held row mr-2 (free)
        __syncthreads();

        float acc0 = 0.f, acc1 = 0.f;   // g1 accumulators across the 2 groups
        for (int grp = 0; grp < 2; ++grp) {
            // ---- h pass: channels grp*8 .. grp*8+7 ----
            if (act) {
                float a0[8] = {}, a1[8] = {};
                for (int dmh = 0; dmh < 3; ++dmh) {
                    int mrow = mr + dmh - 1;
                    if ((unsigned)mrow < 10u) {
                        int sb = (mrow % 3) * 1560;
                        for (int dmw = 0; dmw < 3; ++dmw) {
                            int mcol = wm + dmw - 1;
                            const float* cb = ((unsigned)mcol < 10u)
                                ? &ring[sb + mcol * 156 + bh * 13 + bw0]
                                : &ring[3 * 1560 + bh * 13 + bw0];
                            const float* kb = K1g + (dmh * 3 + dmw) * 144 + grp * 8;
#pragma unroll
                            for (int dbh = 0; dbh < 3; ++dbh) {
                                float w0 = cb[dbh * 13 + 0], w1 = cb[dbh * 13 + 1];
                                float w2v = cb[dbh * 13 + 2], w3 = cb[dbh * 13 + 3];
                                const float* kp = kb + dbh * 48;
#pragma unroll
                                for (int c = 0; c < 8; ++c) {
                                    float k0 = kp[c], k1 = kp[16 + c], k2 = kp[32 + c];
                                    a0[c] = fmaf(k0, w0, fmaf(k1, w1, fmaf(k2, w2v, a0[c])));
                                    a1[c] = fmaf(k0, w1, fmaf(k1, w2v, fmaf(k2, w3, a1[c])));
                                }
                            }
                        }
                    }
                }
#pragma unroll
                for (int c = 0; c < 8; ++c) {
                    float* hp = &hbuf[(c * 10 + wm) * 111 + bh * 11 + bw0];
                    hp[0] = fmaxf(a0[c], 0.f);
                    hp[1] = fmaxf(a1[c], 0.f);
                }
            }
            __syncthreads();

            // ---- g1 accumulate this group (w2a), stays in registers ----
            if (act) {
#pragma unroll
                for (int c = 0; c < 8; ++c) {
                    const float* hb = &hbuf[(c * 10 + wm) * 111];
                    const float* wap = w2a + (grp * 8 + c) * 9;
#pragma unroll
                    for (int dbh = 0; dbh < 3; ++dbh) {
                        int hrow = bh + dbh - 1;
                        bool rok = (unsigned)hrow < 10u;
                        float w[4];
#pragma unroll
                        for (int t = 0; t < 4; ++t) {
                            int col = bw0 - 1 + t;
                            bool ok = rok && ((unsigned)col < 10u);
                            float v = hb[ok ? hrow * 11 + col : 0];
                            w[t] = ok ? v : 0.f;
                        }
                        float k0 = wap[dbh * 3 + 0], k1 = wap[dbh * 3 + 1], k2 = wap[dbh * 3 + 2];
                        acc0 = fmaf(k0, w[0], fmaf(k1, w[1], fmaf(k2, w[2], acc0)));
                        acc1 = fmaf(k0, w[1], fmaf(k1, w[2], fmaf(k2, w[3], acc1)));
                    }
                }
            }
            __syncthreads();   // before next h pass overwrites hbuf
        }

        if (act) {
            float* gp = &g1r[(mr % 3) * 1212 + (wm + 1) * 101 + bh * 10 + bw0];
            gp[0] = acc0; gp[1] = acc1;
        }
        __syncthreads();

        // ---- g2: mem conv 1->1 (w2b) for output row ro = mr-1 ----
        if (mr >= 1) {
            int ro = mr - 1;
            for (int p = tid; p < 1000; p += 512) {
                int wmo = p / 100, bo = p % 100;
                float s = 0.f;
#pragma unroll
                for (int dmh = 0; dmh < 3; ++dmh) {
                    int r2 = ro + dmh - 1;
                    if ((unsigned)r2 < 10u) {
                        const float* gs = &g1r[(r2 % 3) * 1212 + wmo * 101 + bo];
#pragma unroll
                        for (int dmw = 0; dmw < 3; ++dmw)
                            s = fmaf(w2b[dmh * 3 + dmw], gs[dmw * 101], s);
                    }
                }
                out2[(size_t)bn * 10000 + (ro * 10 + wmo) * 100 + bo] = s;
            }
        }
        __syncthreads();
    }
    // ---- final output row ro = 9 ----
    {
        int ro = 9;
        for (int p = tid; p < 1000; p += 512) {
            int wmo = p / 100, bo = p % 100;
            float s = 0.f;
#pragma unroll
            for (int dmh = 0; dmh < 3; ++dmh) {
                int r2 = ro + dmh - 1;
                if ((unsigned)r2 < 10u) {
                    const float* gs = &g1r[(r2 % 3) * 1212 + wmo * 101 + bo];
#pragma unroll
                    for (int dmw = 0; dmw < 3; ++dmw)
                        s = fmaf(w2b[dmh * 3 + dmw], gs[dmw * 101], s);
                }
            }
            out2[(size_t)bn * 10000 + (ro * 10 + wmo) * 100 + bo] = s;
        }
    }
}

// gaussian-normalize over mem axis + softmax + sum over base.
__global__ __launch_bounds__(256) void k_msoft(const float* __restrict__ out2,
                                               float* __restrict__ attnm) {
    __shared__ float tile[10000];
    __shared__ float invS[100];
    int tid = threadIdx.x, bn = blockIdx.x;
    const float* src = out2 + (size_t)bn * 10000;
    for (int i = tid; i < 10000; i += 256) tile[i] = src[i];
    __syncthreads();
    if (tid < 200) {
        int b = tid >> 1, h = tid & 1;
        int m0 = h * 50;
        float s = 0.f, ss = 0.f;
        for (int i = 0; i < 50; ++i) {
            float v = tile[(m0 + i) * 100 + b];
            s += v; ss = fmaf(v, v, ss);
        }
        s += __shfl_xor(s, 1);
        ss += __shfl_xor(ss, 1);
        float mean = s * 0.01f;
        float var = (ss - 100.f * mean * mean) * (1.f / 99.f);
        float istd = 0.2f / sqrtf(var + 1e-5f);  // includes 1/TEMP
        float mx = -1e30f;
        for (int i = 0; i < 50; ++i)
            mx = fmaxf(mx, (tile[(m0 + i) * 100 + b] - mean) * istd);
        mx = fmaxf(mx, __shfl_xor(mx, 1));
        float se = 0.f;
        for (int i = 0; i < 50; ++i) {
            float e = expf((tile[(m0 + i) * 100 + b] - mean) * istd - mx);
            tile[(m0 + i) * 100 + b] = e;
            se += e;
        }
        se += __shfl_xor(se, 1);
        if (h == 0) invS[b] = 1.f / se;
    }
    __syncthreads();
    if (tid < 200) {
        int m = tid >> 1, h = tid & 1;
        float s = 0.f;
        for (int i = 0; i < 50; ++i) {
            int b = h * 50 + i;
            s = fmaf(tile[m * 100 + b], invS[b], s);
        }
        s += __shfl_xor(s, 1);
        if (h == 0) attnm[bn * 100 + m] = s;
    }
}

// grid (64 n, 4 c-chunks), block 128: one c per thread.
__global__ __launch_bounds__(128) void k_attmem(const float* __restrict__ attnm,
                                                const float* __restrict__ feat_m,
                                                float* __restrict__ attm) {
    __shared__ float A[8][100];
    int n = blockIdx.x, cq = blockIdx.y, tid = threadIdx.x;
    for (int i = tid; i < 800; i += 128) {
        int b = i / 100, m = i % 100;
        A[b][m] = attnm[(b * 64 + n) * 100 + m];
    }
    __syncthreads();
    int c = cq * 128 + tid;
    const float* fp = feat_m + ((size_t)n * 512 + c) * 100;
    float acc[8] = {};
    for (int m4 = 0; m4 < 100; m4 += 4) {
        float4 v = *(const float4*)&fp[m4];
#pragma unroll
        for (int b = 0; b < 8; ++b) {
            acc[b] = fmaf(A[b][m4], v.x, acc[b]);
            acc[b] = fmaf(A[b][m4 + 1], v.y, acc[b]);
            acc[b] = fmaf(A[b][m4 + 2], v.z, acc[b]);
            acc[b] = fmaf(A[b][m4 + 3], v.w, acc[b]);
        }
    }
#pragma unroll
    for (int b = 0; b < 8; ++b)
        attm[((size_t)(b * 64 + n)) * 512 + c] = acc[b] * 0.01f;
}

__global__ __launch_bounds__(512) void k_enc(const float* __restrict__ feat_b,
                                             float* __restrict__ enc,
                                             float* __restrict__ encn) {
    __shared__ float red[512];
    int b = blockIdx.x, c = threadIdx.x;
    const float* fp = feat_b + ((size_t)b * 512 + c) * 100;
    float s = 0.f;
    for (int m = 0; m < 100; m += 4) {
        float4 v = *(const float4*)&fp[m];
        s += v.x + v.y + v.z + v.w;
    }
    float e = s * 0.01f;
    enc[b * 512 + c] = e;
    red[c] = e * e;
    __syncthreads();
    for (int o = 256; o; o >>= 1) {
        if (c < o) red[c] += red[c + o];
        __syncthreads();
    }
    if (c == 0) encn[b] = sqrtf(red[0]);
}

__global__ __launch_bounds__(256) void k_final(const float* __restrict__ attm,
                                               const float* __restrict__ enc,
                                               const float* __restrict__ encn,
                                               const float* __restrict__ w_fc,
                                               const float* __restrict__ b_fc,
                                               float* __restrict__ out) {
    __shared__ float attL[64 * 513];
    __shared__ float encL[512];
    __shared__ float mv[512];
    __shared__ float wL[64];
    int b = blockIdx.x, tid = threadIdx.x;
    const float* ap = attm + (size_t)b * 32768;
    for (int i = tid; i < 32768; i += 256) attL[(i >> 9) * 513 + (i & 511)] = ap[i];
    for (int i = tid; i < 512; i += 256) encL[i] = enc[b * 512 + i];
    __syncthreads();
    float escale = 1.f / fmaxf(encn[b], 1e-8f);
    if (tid < 64) {
        int n = tid;
        float ss = 0.f, dp = 0.f;
        for (int c = 0; c < 512; ++c) {
            float a = attL[n * 513 + c];
            ss = fmaf(a, a, ss);
            dp = fmaf(encL[c], a, dp);
        }
        float sc = dp * escale / fmaxf(sqrtf(ss), 1e-8f);
        float mx = sc;
#pragma unroll
        for (int o = 32; o; o >>= 1) mx = fmaxf(mx, __shfl_xor(mx, o));
        float e = expf(sc - mx);
        float se = e;
#pragma unroll
        for (int o = 32; o; o >>= 1) se += __shfl_xor(se, o);
        wL[n] = e / se;
    }
    __syncthreads();
    for (int c = tid; c < 512; c += 256) {
        float s = 0.f;
        for (int n = 0; n < 64; ++n) s = fmaf(wL[n], attL[n * 513 + c], s);
        mv[c] = s;
    }
    __syncthreads();
    for (int k = tid; k < 100; k += 256) {
        const float* wp = w_fc + (size_t)k * 1024;
        float acc = b_fc[k];
        for (int c = 0; c < 512; c += 4) {
            float4 w0 = *(const float4*)&wp[c];
            float4 w1 = *(const float4*)&wp[512 + c];
            acc = fmaf(encL[c], w0.x, acc);     acc = fmaf(encL[c + 1], w0.y, acc);
            acc = fmaf(encL[c + 2], w0.z, acc); acc = fmaf(encL[c + 3], w0.w, acc);
            acc = fmaf(mv[c], w1.x, acc);       acc = fmaf(mv[c + 1], w1.y, acc);
            acc = fmaf(mv[c + 2], w1.z, acc);   acc = fmaf(mv[c + 3], w1.w, acc);
        }
        out[b * 100 + k] = acc;
    }
}

extern "C" void kernel_launch(void* const* d_in, const int* in_sizes, int n_in,
                              void* d_out, int out_size, void* d_ws, size_t ws_size,
                              hipStream_t stream) {
    const float* feat_b = (const float*)d_in[0];
    const float* feat_m = (const float*)d_in[1];
    const float* w1x1   = (const float*)d_in[2];
    const float* gamma  = (const float*)d_in[3];
    const float* beta   = (const float*)d_in[4];
    const float* w1a    = (const float*)d_in[5];
    const float* w1b    = (const float*)d_in[6];
    const float* w2a    = (const float*)d_in[7];
    const float* w2b    = (const float*)d_in[8];
    const float* w_fc   = (const float*)d_in[9];
    const float* b_fc   = (const float*)d_in[10];

    float* ws    = (float*)d_ws;
    float* K1g   = ws;                    // 1296 (pad 1312)
    float* fbp   = ws + 1312;             // 51200
    float* fmp   = fbp + 51200;           // 409600
    float* out2  = fmp + 409600;          // 5120000
    float* attnm = out2 + 5120000;        // 51200
    float* attm  = attnm + 51200;         // 262144
    float* enc   = attm + 262144;         // 4096
    float* encn  = enc + 4096;            // 8

    hipLaunchKernelGGL(k_compose, dim3(1), dim3(256), 0, stream, w1a, w1b, K1g);
    hipLaunchKernelGGL(k_proj2, dim3(72), dim3(512), 0, stream,
                       feat_b, feat_m, w1x1, gamma, beta, fbp, fmp);
    hipLaunchKernelGGL(k_cca, dim3(512), dim3(512), 0, stream, fbp, fmp, K1g, w2a, w2b, out2);
    hipLaunchKernelGGL(k_msoft, dim3(512), dim3(256), 0, stream, out2, attnm);
    hipLaunchKernelGGL(k_attmem, dim3(64, 4), dim3(128), 0, stream, attnm, feat_m, attm);
    hipLaunchKernelGGL(k_enc, dim3(8), dim3(512), 0, stream, feat_b, enc, encn);
    hipLaunchKernelGGL(k_final, dim3(8), dim3(256), 0, stream, attm, enc, encn, w_fc, b_fc, (float*)d_out);
}

// Round 4
// 364.834 us; speedup vs baseline: 1.8839x; 1.2126x over previous
//
#include <hip/hip_runtime.h>
#include <hip/hip_bf16.h>

// ---------------------------------------------------------------------------
// CCAMemoryModel forward, f32 throughout.
//  k_proj2 : per-image tiled GEMM proj (mean-shift+BN+ReLU+L2norm)
//  k_corr  : per (b,n) 100x100x64 GEMM -> corr[bn][m][bpos] (ws, shared with
//            out2 in-place); block 512 also composes K1c.
//  k_cca   : per (b,n): ring-prefetch corr rows (coalesced) -> composed
//            81-tap conv (2 groups of 8 ch, halo'd LDS, no predication)
//            -> g1 (regs) -> g2 -> overwrite corr row in place (lag 2).
//  k_msoft : gaussian-normalize + softmax over mem + sum over base
//  k_attmem: att_mem[b,n,c]
//  k_final : enc (fused) + cosine weights + softmax + mem_vec + linear head
// ---------------------------------------------------------------------------

// One block per image (72 total: 8 feat_b + 64 feat_m).
__global__ __launch_bounds__(512) void k_proj2(const float* __restrict__ feat_b,
                                               const float* __restrict__ feat_m,
                                               const float* __restrict__ w1x1,
                                               const float* __restrict__ gamma,
                                               const float* __restrict__ beta,
                                               float* __restrict__ fbp,
                                               float* __restrict__ fmp) {
    __shared__ __align__(16) float xt[64][104];   // c-tile of x; reused as zbuf
    __shared__ __align__(16) float wt[64][68];    // c-tile of w1x1
    __shared__ float colsum[100];
    __shared__ float wsumL[64];
    __shared__ float invL[100];
    const int tid = threadIdx.x;
    const int img = blockIdx.x;
    const float* x;
    float* outp;
    if (img < 8) { x = feat_b + (size_t)img * 51200; outp = fbp + (size_t)img * 6400; }
    else         { x = feat_m + (size_t)(img - 8) * 51200; outp = fmp + (size_t)(img - 8) * 6400; }

    if (tid < 100) colsum[tid] = 0.f;
    if (tid < 64) wsumL[tid] = 0.f;
    const int r = tid >> 3, q = tid & 7;   // r: out-channel, q: hw-strip
    float acc[13];
#pragma unroll
    for (int j = 0; j < 13; ++j) acc[j] = 0.f;
    __syncthreads();

    for (int ct = 0; ct < 8; ++ct) {
        for (int i = tid; i < 1600; i += 512) {
            int row = i / 25, c4 = (i % 25) * 4;
            *(float4*)&xt[row][c4] = *(const float4*)&x[(size_t)(ct * 64 + row) * 100 + c4];
        }
        for (int i = tid; i < 1024; i += 512) {
            int row = i / 16, c4 = (i % 16) * 4;
            *(float4*)&wt[row][c4] = *(const float4*)&w1x1[(size_t)row * 512 + ct * 64 + c4];
        }
        __syncthreads();
        if (tid < 100) {
            float s = 0.f;
            for (int c = 0; c < 64; ++c) s += xt[c][tid];
            colsum[tid] += s;
        }
        if (tid < 64) {
            float s = 0.f;
            for (int c = 0; c < 64; ++c) s += wt[tid][c];
            wsumL[tid] += s;
        }
        for (int c = 0; c < 64; ++c) {
            float w = wt[r][c];
#pragma unroll
            for (int j = 0; j < 13; ++j) {
                int hw = q + 8 * j;
                if (hw < 100) acc[j] = fmaf(w, xt[c][hw], acc[j]);
            }
        }
        __syncthreads();
    }
    float g = gamma[r], be = beta[r], wsr = wsumL[r];
#pragma unroll
    for (int j = 0; j < 13; ++j) {
        int hw = q + 8 * j;
        if (hw < 100) {
            float mean = colsum[hw] * (1.f / 512.f);
            xt[r][hw] = fmaxf((acc[j] - mean * wsr) * g + be, 0.f);
        }
    }
    __syncthreads();
    if (tid < 100) {
        float ss = 0.f;
        for (int rr = 0; rr < 64; ++rr) { float z = xt[rr][tid]; ss = fmaf(z, z, ss); }
        invL[tid] = 1.f / fmaxf(sqrtf(ss), 1e-8f);
    }
    __syncthreads();
    for (int i = tid; i < 6400; i += 512) {
        int rr = i / 100, hw = i % 100;
        outp[i] = xt[rr][hw] * invL[hw];
    }
}

// Blocks 0..511: corr[bn][m][b] = sum_r fm[n][r][m]*fb[b'][r][b].
// Block 512: compose K1c[dm*144 + grp*72 + db*8 + (o&7)].
__global__ __launch_bounds__(512) void k_corr(const float* __restrict__ fbp,
                                              const float* __restrict__ fmp,
                                              const float* __restrict__ w1a,
                                              const float* __restrict__ w1b,
                                              float* __restrict__ K1c,
                                              float* __restrict__ corr) {
    if (blockIdx.x == 512) {
        for (int t = threadIdx.x; t < 1296; t += 512) {
            int dm = t / 144, rr = t % 144;
            int grp = rr / 72; rr %= 72;
            int db = rr / 8, c8 = rr % 8;
            int o = grp * 8 + c8;
            float s = 0.f;
            for (int c = 0; c < 16; ++c)
                s += w1b[(o * 16 + c) * 9 + dm] * w1a[c * 9 + db];
            K1c[t] = s;
        }
        return;
    }
    __shared__ __align__(16) float A[6400];
    __shared__ __align__(16) float B[6400];
    const int tid = threadIdx.x, bn = blockIdx.x;
    const float* fm = fmp + (size_t)(bn & 63) * 6400;
    const float* fb = fbp + (size_t)(bn >> 6) * 6400;
    for (int i = tid * 4; i < 6400; i += 2048) {
        *(float4*)&A[i] = *(const float4*)&fm[i];
        *(float4*)&B[i] = *(const float4*)&fb[i];
    }
    __syncthreads();
    float* dst = corr + (size_t)bn * 10000;
    for (int u = tid; u < 625; u += 512) {
        int m0 = (u / 25) * 4, b0 = (u % 25) * 4;
        float acc[4][4] = {};
        for (int r = 0; r < 64; ++r) {
            float4 av = *(const float4*)&A[r * 100 + m0];
            float4 bv = *(const float4*)&B[r * 100 + b0];
            float a[4] = {av.x, av.y, av.z, av.w};
            float bb[4] = {bv.x, bv.y, bv.z, bv.w};
#pragma unroll
            for (int i = 0; i < 4; ++i)
#pragma unroll
                for (int j = 0; j < 4; ++j) acc[i][j] = fmaf(a[i], bb[j], acc[i][j]);
        }
#pragma unroll
        for (int i = 0; i < 4; ++i)
#pragma unroll
            for (int j = 0; j < 4; ++j) dst[(m0 + i) * 100 + (b0 + j)] = acc[i][j];
    }
}

// Main conv kernel. In-place: reads corr rows, writes out2 rows (lag 2).
// ring: 3 slots [10 mcol][12 rows][14 cols] + zero slab (halo'd, stored+1).
// hbuf: [8 c][10 wm][12][12] halo'd. g1r: 3 slots [12 wm][100].
__global__ __launch_bounds__(512, 4) void k_cca(float* corr,
                                                const float* __restrict__ K1c,
                                                const float* __restrict__ w2a,
                                                const float* __restrict__ w2b) {
    __shared__ __align__(16) float ring[3 * 1680 + 168];  // 5208 f32
    __shared__ __align__(16) float hbuf[8 * 10 * 12 * 12]; // 11520 f32
    __shared__ __align__(16) float g1r[3 * 1200];          // 3600 f32
    const int tid = threadIdx.x;
    const int bn = blockIdx.x;
    float* cb_bn = corr + (size_t)bn * 10000;

    for (int i = tid; i < 5208; i += 512) ring[i] = 0.f;
    for (int i = tid; i < 11520; i += 512) hbuf[i] = 0.f;
    for (int i = tid; i < 3600; i += 512) g1r[i] = 0.f;
    // load corr row 0 into slot 0
    for (int i = tid; i < 1000; i += 512) {
        int mcol = i / 100, rr = (i % 100) / 10, cl = i % 10;
        ring[mcol * 168 + (rr + 1) * 14 + (cl + 1)] = cb_bn[i];
    }
    __syncthreads();

    const bool act = tid < 500;
    int wm = 0, bh = 0, bw0 = 0;
    if (act) { wm = tid / 50; int rr = tid % 50; bh = rr / 5; bw0 = (rr % 5) * 2; }

    for (int mr = 0; mr < 10; ++mr) {
        // ---- prefetch corr row mr+1 (coalesced) ----
        if (mr < 9) {
            const float* src = cb_bn + (mr + 1) * 1000;
            int sb = ((mr + 1) % 3) * 1680;
            for (int i = tid; i < 1000; i += 512) {
                int mcol = i / 100, rr = (i % 100) / 10, cl = i % 10;
                ring[sb + mcol * 168 + (rr + 1) * 14 + (cl + 1)] = src[i];
            }
        }
        __syncthreads();

        float gacc0 = 0.f, gacc1 = 0.f;
        for (int grp = 0; grp < 2; ++grp) {
            // ---- h pass: channels grp*8..+7, no predication (halo) ----
            if (act) {
                float a0[8] = {}, a1[8] = {};
                for (int dmh = 0; dmh < 3; ++dmh) {
                    int mrow = mr + dmh - 1;
                    if ((unsigned)mrow < 10u) {
                        int sb = (mrow % 3) * 1680;
#pragma unroll
                        for (int dmw = 0; dmw < 3; ++dmw) {
                            int mcol = wm + dmw - 1;
                            const float* cw = ((unsigned)mcol < 10u)
                                ? &ring[sb + mcol * 168 + bh * 14 + bw0]
                                : &ring[3 * 1680 + bh * 14 + bw0];
                            const float* kb = K1c + (dmh * 3 + dmw) * 144 + grp * 72;
#pragma unroll
                            for (int dbh = 0; dbh < 3; ++dbh) {
                                float2 lo = *(const float2*)&cw[dbh * 14];
                                float2 hi = *(const float2*)&cw[dbh * 14 + 2];
                                const float* kp = kb + dbh * 24;
#pragma unroll
                                for (int c = 0; c < 8; ++c) {
                                    float k0 = kp[c], k1 = kp[8 + c], k2 = kp[16 + c];
                                    a0[c] = fmaf(k0, lo.x, fmaf(k1, lo.y, fmaf(k2, hi.x, a0[c])));
                                    a1[c] = fmaf(k0, lo.y, fmaf(k1, hi.x, fmaf(k2, hi.y, a1[c])));
                                }
                            }
                        }
                    }
                }
#pragma unroll
                for (int c = 0; c < 8; ++c) {
                    int hi_ = ((c * 10 + wm) * 12 + (bh + 1)) * 12 + (bw0 + 1);
                    hbuf[hi_] = fmaxf(a0[c], 0.f);
                    hbuf[hi_ + 1] = fmaxf(a1[c], 0.f);
                }
            }
            __syncthreads();

            // ---- g1 accumulate (w2a), halo'd -> no predication ----
            if (act) {
#pragma unroll
                for (int c = 0; c < 8; ++c) {
                    const float* hb = &hbuf[((c * 10 + wm) * 12 + bh) * 12 + bw0];
                    const float* wap = w2a + (grp * 8 + c) * 9;
#pragma unroll
                    for (int dbh = 0; dbh < 3; ++dbh) {
                        float2 lo = *(const float2*)&hb[dbh * 12];
                        float2 hi = *(const float2*)&hb[dbh * 12 + 2];
                        float k0 = wap[dbh * 3], k1 = wap[dbh * 3 + 1], k2 = wap[dbh * 3 + 2];
                        gacc0 = fmaf(k0, lo.x, fmaf(k1, lo.y, fmaf(k2, hi.x, gacc0)));
                        gacc1 = fmaf(k0, lo.y, fmaf(k1, hi.x, fmaf(k2, hi.y, gacc1)));
                    }
                }
                if (grp == 1) {
                    int gi = (mr % 3) * 1200 + (wm + 1) * 100 + bh * 10 + bw0;
                    g1r[gi] = gacc0;
                    g1r[gi + 1] = gacc1;
                }
            }
            __syncthreads();
        }

        // ---- g2: mem conv (w2b), write out2 row ro = mr-1 in place ----
        if (mr >= 1) {
            int ro = mr - 1;
            for (int p = tid; p < 1000; p += 512) {
                int wmo = p / 100, bo = p % 100;
                float s = 0.f;
#pragma unroll
                for (int dmh = 0; dmh < 3; ++dmh) {
                    int r2 = ro + dmh - 1;
                    if ((unsigned)r2 < 10u) {
                        const float* gs = &g1r[(r2 % 3) * 1200 + wmo * 100 + bo];
                        s = fmaf(w2b[dmh * 3 + 0], gs[0], s);
                        s = fmaf(w2b[dmh * 3 + 1], gs[100], s);
                        s = fmaf(w2b[dmh * 3 + 2], gs[200], s);
                    }
                }
                cb_bn[ro * 1000 + wmo * 100 + bo] = s;
            }
        }
        __syncthreads();
    }
    // ---- final row ro = 9 ----
    {
        int ro = 9;
        for (int p = tid; p < 1000; p += 512) {
            int wmo = p / 100, bo = p % 100;
            float s = 0.f;
#pragma unroll
            for (int dmh = 0; dmh < 3; ++dmh) {
                int r2 = ro + dmh - 1;
                if ((unsigned)r2 < 10u) {
                    const float* gs = &g1r[(r2 % 3) * 1200 + wmo * 100 + bo];
                    s = fmaf(w2b[dmh * 3 + 0], gs[0], s);
                    s = fmaf(w2b[dmh * 3 + 1], gs[100], s);
                    s = fmaf(w2b[dmh * 3 + 2], gs[200], s);
                }
            }
            cb_bn[ro * 1000 + wmo * 100 + bo] = s;
        }
    }
}

// gaussian-normalize over mem axis + softmax + sum over base.
__global__ __launch_bounds__(256) void k_msoft(const float* __restrict__ out2,
                                               float* __restrict__ attnm) {
    __shared__ float tile[10000];
    __shared__ float invS[100];
    int tid = threadIdx.x, bn = blockIdx.x;
    const float* src = out2 + (size_t)bn * 10000;
    for (int i = tid; i < 10000; i += 256) tile[i] = src[i];
    __syncthreads();
    if (tid < 200) {
        int b = tid >> 1, h = tid & 1;
        int m0 = h * 50;
        float s = 0.f, ss = 0.f;
        for (int i = 0; i < 50; ++i) {
            float v = tile[(m0 + i) * 100 + b];
            s += v; ss = fmaf(v, v, ss);
        }
        s += __shfl_xor(s, 1);
        ss += __shfl_xor(ss, 1);
        float mean = s * 0.01f;
        float var = (ss - 100.f * mean * mean) * (1.f / 99.f);
        float istd = 0.2f / sqrtf(var + 1e-5f);  // includes 1/TEMP
        float mx = -1e30f;
        for (int i = 0; i < 50; ++i)
            mx = fmaxf(mx, (tile[(m0 + i) * 100 + b] - mean) * istd);
        mx = fmaxf(mx, __shfl_xor(mx, 1));
        float se = 0.f;
        for (int i = 0; i < 50; ++i) {
            float e = expf((tile[(m0 + i) * 100 + b] - mean) * istd - mx);
            tile[(m0 + i) * 100 + b] = e;
            se += e;
        }
        se += __shfl_xor(se, 1);
        if (h == 0) invS[b] = 1.f / se;
    }
    __syncthreads();
    if (tid < 200) {
        int m = tid >> 1, h = tid & 1;
        float s = 0.f;
        for (int i = 0; i < 50; ++i) {
            int b = h * 50 + i;
            s = fmaf(tile[m * 100 + b], invS[b], s);
        }
        s += __shfl_xor(s, 1);
        if (h == 0) attnm[bn * 100 + m] = s;
    }
}

// grid (64 n, 4 c-chunks), block 128.
__global__ __launch_bounds__(128) void k_attmem(const float* __restrict__ attnm,
                                                const float* __restrict__ feat_m,
                                                float* __restrict__ attm) {
    __shared__ float A[8][100];
    int n = blockIdx.x, cq = blockIdx.y, tid = threadIdx.x;
    for (int i = tid; i < 800; i += 128) {
        int b = i / 100, m = i % 100;
        A[b][m] = attnm[(b * 64 + n) * 100 + m];
    }
    __syncthreads();
    int c = cq * 128 + tid;
    const float* fp = feat_m + ((size_t)n * 512 + c) * 100;
    float acc[8] = {};
    for (int m4 = 0; m4 < 100; m4 += 4) {
        float4 v = *(const float4*)&fp[m4];
#pragma unroll
        for (int b = 0; b < 8; ++b) {
            acc[b] = fmaf(A[b][m4], v.x, acc[b]);
            acc[b] = fmaf(A[b][m4 + 1], v.y, acc[b]);
            acc[b] = fmaf(A[b][m4 + 2], v.z, acc[b]);
            acc[b] = fmaf(A[b][m4 + 3], v.w, acc[b]);
        }
    }
#pragma unroll
    for (int b = 0; b < 8; ++b)
        attm[((size_t)(b * 64 + n)) * 512 + c] = acc[b] * 0.01f;
}

// Fused enc + memory-wrap head. One block per b (8 blocks, 512 threads).
__global__ __launch_bounds__(512) void k_final(const float* __restrict__ feat_b,
                                               const float* __restrict__ attm,
                                               const float* __restrict__ w_fc,
                                               const float* __restrict__ b_fc,
                                               float* __restrict__ out) {
    __shared__ float attL[64 * 513];
    __shared__ float encL[512];
    __shared__ float mv[512];
    __shared__ float wL[64];
    __shared__ float red[512];
    int b = blockIdx.x, tid = threadIdx.x;
    // enc = spatial mean of feat_b[b]
    {
        const float* fp = feat_b + ((size_t)b * 512 + tid) * 100;
        float s = 0.f;
        for (int m = 0; m < 100; m += 4) {
            float4 v = *(const float4*)&fp[m];
            s += v.x + v.y + v.z + v.w;
        }
        float e = s * 0.01f;
        encL[tid] = e;
        red[tid] = e * e;
    }
    const float* ap = attm + (size_t)b * 32768;
    for (int i = tid; i < 32768; i += 512) attL[(i >> 9) * 513 + (i & 511)] = ap[i];
    __syncthreads();
    for (int o = 256; o; o >>= 1) {
        if (tid < o) red[tid] += red[tid + o];
        __syncthreads();
    }
    float escale = 1.f / fmaxf(sqrtf(red[0]), 1e-8f);
    if (tid < 64) {
        int n = tid;
        float ss = 0.f, dp = 0.f;
        for (int c = 0; c < 512; ++c) {
            float a = attL[n * 513 + c];
            ss = fmaf(a, a, ss);
            dp = fmaf(encL[c], a, dp);
        }
        float sc = dp * escale / fmaxf(sqrtf(ss), 1e-8f);
        float mx = sc;
#pragma unroll
        for (int o = 32; o; o >>= 1) mx = fmaxf(mx, __shfl_xor(mx, o));
        float e = expf(sc - mx);
        float se = e;
#pragma unroll
        for (int o = 32; o; o >>= 1) se += __shfl_xor(se, o);
        wL[n] = e / se;
    }
    __syncthreads();
    {
        int c = tid;
        float s = 0.f;
        for (int n = 0; n < 64; ++n) s = fmaf(wL[n], attL[n * 513 + c], s);
        mv[c] = s;
    }
    __syncthreads();
    for (int k = tid; k < 100; k += 512) {
        const float* wp = w_fc + (size_t)k * 1024;
        float acc = b_fc[k];
        for (int c = 0; c < 512; c += 4) {
            float4 w0 = *(const float4*)&wp[c];
            float4 w1 = *(const float4*)&wp[512 + c];
            acc = fmaf(encL[c], w0.x, acc);     acc = fmaf(encL[c + 1], w0.y, acc);
            acc = fmaf(encL[c + 2], w0.z, acc); acc = fmaf(encL[c + 3], w0.w, acc);
            acc = fmaf(mv[c], w1.x, acc);       acc = fmaf(mv[c + 1], w1.y, acc);
            acc = fmaf(mv[c + 2], w1.z, acc);   acc = fmaf(mv[c + 3], w1.w, acc);
        }
        out[b * 100 + k] = acc;
    }
}

extern "C" void kernel_launch(void* const* d_in, const int* in_sizes, int n_in,
                              void* d_out, int out_size, void* d_ws, size_t ws_size,
                              hipStream_t stream) {
    const float* feat_b = (const float*)d_in[0];
    const float* feat_m = (const float*)d_in[1];
    const float* w1x1   = (const float*)d_in[2];
    const float* gamma  = (const float*)d_in[3];
    const float* beta   = (const float*)d_in[4];
    const float* w1a    = (const float*)d_in[5];
    const float* w1b    = (const float*)d_in[6];
    const float* w2a    = (const float*)d_in[7];
    const float* w2b    = (const float*)d_in[8];
    const float* w_fc   = (const float*)d_in[9];
    const float* b_fc   = (const float*)d_in[10];

    float* ws    = (float*)d_ws;
    float* K1c   = ws;                    // 1296 (pad 1312)
    float* fbp   = ws + 1312;             // 51200
    float* fmp   = fbp + 51200;           // 409600
    float* corr  = fmp + 409600;          // 5120000  (corr, overwritten as out2)
    float* attnm = corr + 5120000;        // 51200
    float* attm  = attnm + 51200;         // 262144

    hipLaunchKernelGGL(k_proj2, dim3(72), dim3(512), 0, stream,
                       feat_b, feat_m, w1x1, gamma, beta, fbp, fmp);
    hipLaunchKernelGGL(k_corr, dim3(513), dim3(512), 0, stream,
                       fbp, fmp, w1a, w1b, K1c, corr);
    hipLaunchKernelGGL(k_cca, dim3(512), dim3(512), 0, stream, corr, K1c, w2a, w2b);
    hipLaunchKernelGGL(k_msoft, dim3(512), dim3(256), 0, stream, corr, attnm);
    hipLaunchKernelGGL(k_attmem, dim3(64, 4), dim3(128), 0, stream, attnm, feat_m, attm);
    hipLaunchKernelGGL(k_final, dim3(8), dim3(512), 0, stream,
                       feat_b, attm, w_fc, b_fc, (float*)d_out);
}

// Round 5
// 349.803 us; speedup vs baseline: 1.9648x; 1.0430x over previous
//
#include <hip/hip_runtime.h>
#include <hip/hip_bf16.h>

// ---------------------------------------------------------------------------
// CCAMemoryModel forward, f32 throughout.
//  k_proj2 : per-image tiled GEMM proj (mean-shift+BN+ReLU+L2norm)
//  k_corr  : per (b,n) 100x100x64 GEMM -> corr[bn][m][bpos]; block 512
//            composes K1c (block1 collapsed to one 81-tap conv).
//  k_cca   : ONE WAVE per (bn, wm) strip. Ring-prefetch 3 corr mcols/row,
//            single-pass 16-ch composed conv in regs, g1 base-conv via
//            in-wave shuffles (partial row sums). No barriers, no hbuf.
//            Writes g1[bn][m][bpos].
//  k_msoft2: fused g2 mem-conv (w2b) + gaussian-normalize + softmax over mem
//            + sum over base -> attn_memory.
//  k_attmem: att_mem[b,n,c]
//  k_final : enc (fused) + cosine weights + softmax + mem_vec + linear head
// ---------------------------------------------------------------------------

// One block per image (72 total: 8 feat_b + 64 feat_m).
__global__ __launch_bounds__(512) void k_proj2(const float* __restrict__ feat_b,
                                               const float* __restrict__ feat_m,
                                               const float* __restrict__ w1x1,
                                               const float* __restrict__ gamma,
                                               const float* __restrict__ beta,
                                               float* __restrict__ fbp,
                                               float* __restrict__ fmp) {
    __shared__ __align__(16) float xt[64][104];   // c-tile of x; reused as zbuf
    __shared__ __align__(16) float wt[64][68];    // c-tile of w1x1
    __shared__ float colsum[100];
    __shared__ float wsumL[64];
    __shared__ float invL[100];
    const int tid = threadIdx.x;
    const int img = blockIdx.x;
    const float* x;
    float* outp;
    if (img < 8) { x = feat_b + (size_t)img * 51200; outp = fbp + (size_t)img * 6400; }
    else         { x = feat_m + (size_t)(img - 8) * 51200; outp = fmp + (size_t)(img - 8) * 6400; }

    if (tid < 100) colsum[tid] = 0.f;
    if (tid < 64) wsumL[tid] = 0.f;
    const int r = tid >> 3, q = tid & 7;   // r: out-channel, q: hw-strip
    float acc[13];
#pragma unroll
    for (int j = 0; j < 13; ++j) acc[j] = 0.f;
    __syncthreads();

    for (int ct = 0; ct < 8; ++ct) {
        for (int i = tid; i < 1600; i += 512) {
            int row = i / 25, c4 = (i % 25) * 4;
            *(float4*)&xt[row][c4] = *(const float4*)&x[(size_t)(ct * 64 + row) * 100 + c4];
        }
        for (int i = tid; i < 1024; i += 512) {
            int row = i / 16, c4 = (i % 16) * 4;
            *(float4*)&wt[row][c4] = *(const float4*)&w1x1[(size_t)row * 512 + ct * 64 + c4];
        }
        __syncthreads();
        if (tid < 100) {
            float s = 0.f;
            for (int c = 0; c < 64; ++c) s += xt[c][tid];
            colsum[tid] += s;
        }
        if (tid < 64) {
            float s = 0.f;
            for (int c = 0; c < 64; ++c) s += wt[tid][c];
            wsumL[tid] += s;
        }
        for (int c = 0; c < 64; ++c) {
            float w = wt[r][c];
#pragma unroll
            for (int j = 0; j < 13; ++j) {
                int hw = q + 8 * j;
                if (hw < 100) acc[j] = fmaf(w, xt[c][hw], acc[j]);
            }
        }
        __syncthreads();
    }
    float g = gamma[r], be = beta[r], wsr = wsumL[r];
#pragma unroll
    for (int j = 0; j < 13; ++j) {
        int hw = q + 8 * j;
        if (hw < 100) {
            float mean = colsum[hw] * (1.f / 512.f);
            xt[r][hw] = fmaxf((acc[j] - mean * wsr) * g + be, 0.f);
        }
    }
    __syncthreads();
    if (tid < 100) {
        float ss = 0.f;
        for (int rr = 0; rr < 64; ++rr) { float z = xt[rr][tid]; ss = fmaf(z, z, ss); }
        invL[tid] = 1.f / fmaxf(sqrtf(ss), 1e-8f);
    }
    __syncthreads();
    for (int i = tid; i < 6400; i += 512) {
        int rr = i / 100, hw = i % 100;
        outp[i] = xt[rr][hw] * invL[hw];
    }
}

// Blocks 0..511: corr[bn][m][b] = sum_r fm[r][m]*fb[r][b].
// Block 512: compose K1c[dm*144 + db*16 + c] = sum_c' w1b[c,c',dm]*w1a[c',db].
__global__ __launch_bounds__(512) void k_corr(const float* __restrict__ fbp,
                                              const float* __restrict__ fmp,
                                              const float* __restrict__ w1a,
                                              const float* __restrict__ w1b,
                                              float* __restrict__ K1c,
                                              float* __restrict__ corr) {
    if (blockIdx.x == 512) {
        for (int t = threadIdx.x; t < 1296; t += 512) {
            int dm = t / 144, rem = t % 144;
            int db = rem / 16, c = rem % 16;
            float s = 0.f;
            for (int cp = 0; cp < 16; ++cp)
                s += w1b[(c * 16 + cp) * 9 + dm] * w1a[cp * 9 + db];
            K1c[t] = s;
        }
        return;
    }
    __shared__ __align__(16) float A[6400];
    __shared__ __align__(16) float B[6400];
    const int tid = threadIdx.x, bn = blockIdx.x;
    const float* fm = fmp + (size_t)(bn & 63) * 6400;
    const float* fb = fbp + (size_t)(bn >> 6) * 6400;
    for (int i = tid * 4; i < 6400; i += 2048) {
        *(float4*)&A[i] = *(const float4*)&fm[i];
        *(float4*)&B[i] = *(const float4*)&fb[i];
    }
    __syncthreads();
    float* dst = corr + (size_t)bn * 10000;
    for (int u = tid; u < 625; u += 512) {
        int m0 = (u / 25) * 4, b0 = (u % 25) * 4;
        float acc[4][4] = {};
        for (int r = 0; r < 64; ++r) {
            float4 av = *(const float4*)&A[r * 100 + m0];
            float4 bv = *(const float4*)&B[r * 100 + b0];
            float a[4] = {av.x, av.y, av.z, av.w};
            float bb[4] = {bv.x, bv.y, bv.z, bv.w};
#pragma unroll
            for (int i = 0; i < 4; ++i)
#pragma unroll
                for (int j = 0; j < 4; ++j) acc[i][j] = fmaf(a[i], bb[j], acc[i][j]);
        }
#pragma unroll
        for (int i = 0; i < 4; ++i)
#pragma unroll
            for (int j = 0; j < 4; ++j) dst[(m0 + i) * 100 + (b0 + j)] = acc[i][j];
    }
}

// One wave per (wm, bn) strip. grid (10, 512), block 64.
// ring: 4 slots x [3 mcols][12 rows][14 cols] + zero slab. 2184 f32 = 8.7 KB.
__global__ __launch_bounds__(64, 4) void k_cca(const float* __restrict__ corr,
                                               const float* __restrict__ K1c,
                                               const float* __restrict__ w2a,
                                               float* __restrict__ g1out) {
    __shared__ float ring[2184];   // zero slab at 2016
    const int lane = threadIdx.x;
    const int wm = blockIdx.x, bn = blockIdx.y;
    const int u = lane < 50 ? lane : 49;   // clamp spare lanes
    const int bh = u / 5, p = u % 5, bw0 = 2 * p;
    const bool act = lane < 50;

    for (int i = lane; i < 2184; i += 64) ring[i] = 0.f;
    const float* cbase = corr + (size_t)bn * 10000 + (wm - 1) * 100;
    const int i0 = (wm == 0) ? 100 : 0;
    const int i1 = (wm == 9) ? 200 : 300;

    auto prefetch = [&](int R) {
        if (R > 9) return;
        const float* src = cbase + R * 1000;
        float* dslot = &ring[(R & 3) * 504];
#pragma unroll
        for (int k = 0; k < 5; ++k) {
            int i = lane + k * 64;
            if (i >= i0 && i < i1) {
                int mc = i / 100, t = i % 100;
                dslot[mc * 168 + (t / 10 + 1) * 14 + (t % 10 + 1)] = src[i];
            }
        }
    };
    prefetch(0);
    prefetch(1);
    // single-wave block: DS ops are in-order per wave; no barrier needed.

    const int rbase = bh * 14 + bw0;
    for (int mr = 0; mr < 10; ++mr) {
        prefetch(mr + 2);

        // ---- h pass: all 16 channels in registers ----
        float a0[16], a1[16];
#pragma unroll
        for (int c = 0; c < 16; ++c) { a0[c] = 0.f; a1[c] = 0.f; }
        for (int dmh = 0; dmh < 3; ++dmh) {
            int mrow = mr + dmh - 1;
            if ((unsigned)mrow >= 10u) continue;
            const float* slab0 = &ring[(mrow & 3) * 504];
#pragma unroll
            for (int dmw = 0; dmw < 3; ++dmw) {
                bool mv = (unsigned)(wm + dmw - 1) < 10u;
                const float* cb = (mv ? slab0 + dmw * 168 : &ring[2016]) + rbase;
                const float* kp = K1c + (dmh * 3 + dmw) * 144;
#pragma unroll
                for (int dbh = 0; dbh < 3; ++dbh) {
                    float2 lo = *(const float2*)&cb[dbh * 14];
                    float2 hi = *(const float2*)&cb[dbh * 14 + 2];
                    const float* kq = kp + dbh * 48;
#pragma unroll
                    for (int c = 0; c < 16; ++c) {
                        float k0 = kq[c], k1 = kq[16 + c], k2 = kq[32 + c];
                        a0[c] = fmaf(k0, lo.x, fmaf(k1, lo.y, fmaf(k2, hi.x, a0[c])));
                        a1[c] = fmaf(k0, lo.y, fmaf(k1, hi.x, fmaf(k2, hi.y, a1[c])));
                    }
                }
            }
        }

        // ---- g1 base-conv via in-wave shuffles (partial row sums) ----
        float P00 = 0.f, P01 = 0.f, P10 = 0.f, P11 = 0.f, P20 = 0.f, P21 = 0.f;
#pragma unroll
        for (int c = 0; c < 16; ++c) {
            float r0 = fmaxf(a0[c], 0.f), r1 = fmaxf(a1[c], 0.f);
            float lA = __shfl(r1, lane - 1); lA = (p > 0) ? lA : 0.f;   // col bw0-1
            float rA = __shfl(r0, lane + 1); rA = (p < 4) ? rA : 0.f;   // col bw0+2
            const float* wq = w2a + c * 9;
            P00 = fmaf(wq[0], lA, fmaf(wq[1], r0, fmaf(wq[2], r1, P00)));
            P01 = fmaf(wq[0], r0, fmaf(wq[1], r1, fmaf(wq[2], rA, P01)));
            P10 = fmaf(wq[3], lA, fmaf(wq[4], r0, fmaf(wq[5], r1, P10)));
            P11 = fmaf(wq[3], r0, fmaf(wq[4], r1, fmaf(wq[5], rA, P11)));
            P20 = fmaf(wq[6], lA, fmaf(wq[7], r0, fmaf(wq[8], r1, P20)));
            P21 = fmaf(wq[6], r0, fmaf(wq[7], r1, fmaf(wq[8], rA, P21)));
        }
        // out row bh takes: P0 from row bh-1 (lane-5), own P1, P2 from row bh+1.
        float u00 = __shfl(P00, lane - 5), u01 = __shfl(P01, lane - 5);
        float u20 = __shfl(P20, lane + 5), u21 = __shfl(P21, lane + 5);
        if (bh == 0) { u00 = 0.f; u01 = 0.f; }
        if (bh == 9) { u20 = 0.f; u21 = 0.f; }
        float g0 = P10 + u00 + u20;
        float g1v = P11 + u01 + u21;
        if (act) {
            float2 st; st.x = g0; st.y = g1v;
            *(float2*)&g1out[(size_t)bn * 10000 + (mr * 10 + wm) * 100 + bh * 10 + bw0] = st;
        }
    }
}

// Fused g2 (w2b mem-conv) + gaussian-normalize over mem + softmax + sum over
// base. One block per bn (512 x 512 thr).
__global__ __launch_bounds__(512) void k_msoft2(const float* __restrict__ g1,
                                                const float* __restrict__ w2b,
                                                float* __restrict__ attnm) {
    __shared__ float gt[10000];
    const int tid = threadIdx.x, bn = blockIdx.x;
    const float* src = g1 + (size_t)bn * 10000;
    for (int i = tid; i < 10000; i += 512) gt[i] = src[i];
    __syncthreads();
    float wb[9];
#pragma unroll
    for (int t = 0; t < 9; ++t) wb[t] = w2b[t];
    const int b = tid >> 2, q = tid & 3;
    const bool act = tid < 400;
    float ev[25];
    float se = 0.f;
    if (act) {
        float s = 0.f, ss = 0.f;
#pragma unroll
        for (int i = 0; i < 25; ++i) {
            int m = q * 25 + i, mh = m / 10, mw = m % 10;
            float v = 0.f;
#pragma unroll
            for (int dh = 0; dh < 3; ++dh) {
                int rr = mh + dh - 1;
                if ((unsigned)rr < 10u) {
#pragma unroll
                    for (int dw = 0; dw < 3; ++dw) {
                        int ww = mw + dw - 1;
                        if ((unsigned)ww < 10u)
                            v = fmaf(wb[dh * 3 + dw], gt[(rr * 10 + ww) * 100 + b], v);
                    }
                }
            }
            ev[i] = v;
            s += v; ss = fmaf(v, v, ss);
        }
        s += __shfl_xor(s, 1); s += __shfl_xor(s, 2);
        ss += __shfl_xor(ss, 1); ss += __shfl_xor(ss, 2);
        float mean = s * 0.01f;
        float var = (ss - 100.f * mean * mean) * (1.f / 99.f);
        float istd = 0.2f / sqrtf(var + 1e-5f);  // includes 1/TEMP
        float mx = -1e30f;
#pragma unroll
        for (int i = 0; i < 25; ++i) mx = fmaxf(mx, ev[i]);
        mx = fmaxf(mx, __shfl_xor(mx, 1)); mx = fmaxf(mx, __shfl_xor(mx, 2));
#pragma unroll
        for (int i = 0; i < 25; ++i) {
            float e = expf((ev[i] - mx) * istd);
            ev[i] = e; se += e;
        }
        se += __shfl_xor(se, 1); se += __shfl_xor(se, 2);
    }
    __syncthreads();   // all conv reads of gt done
    if (act) {
        float inv = 1.f / se;
#pragma unroll
        for (int i = 0; i < 25; ++i) gt[(q * 25 + i) * 100 + b] = ev[i] * inv;
    }
    __syncthreads();
    if (act) {
        int m = tid >> 2;
        float s2 = 0.f;
#pragma unroll
        for (int i = 0; i < 25; ++i) s2 += gt[m * 100 + q * 25 + i];
        s2 += __shfl_xor(s2, 1); s2 += __shfl_xor(s2, 2);
        if (q == 0) attnm[bn * 100 + m] = s2;
    }
}

// grid (64 n, 4 c-chunks), block 128.
__global__ __launch_bounds__(128) void k_attmem(const float* __restrict__ attnm,
                                                const float* __restrict__ feat_m,
                                                float* __restrict__ attm) {
    __shared__ float A[8][100];
    int n = blockIdx.x, cq = blockIdx.y, tid = threadIdx.x;
    for (int i = tid; i < 800; i += 128) {
        int b = i / 100, m = i % 100;
        A[b][m] = attnm[(b * 64 + n) * 100 + m];
    }
    __syncthreads();
    int c = cq * 128 + tid;
    const float* fp = feat_m + ((size_t)n * 512 + c) * 100;
    float acc[8] = {};
    for (int m4 = 0; m4 < 100; m4 += 4) {
        float4 v = *(const float4*)&fp[m4];
#pragma unroll
        for (int b = 0; b < 8; ++b) {
            acc[b] = fmaf(A[b][m4], v.x, acc[b]);
            acc[b] = fmaf(A[b][m4 + 1], v.y, acc[b]);
            acc[b] = fmaf(A[b][m4 + 2], v.z, acc[b]);
            acc[b] = fmaf(A[b][m4 + 3], v.w, acc[b]);
        }
    }
#pragma unroll
    for (int b = 0; b < 8; ++b)
        attm[((size_t)(b * 64 + n)) * 512 + c] = acc[b] * 0.01f;
}

// Fused enc + memory-wrap head. One block per b (8 blocks, 512 threads).
__global__ __launch_bounds__(512) void k_final(const float* __restrict__ feat_b,
                                               const float* __restrict__ attm,
                                               const float* __restrict__ w_fc,
                                               const float* __restrict__ b_fc,
                                               float* __restrict__ out) {
    __shared__ float attL[64 * 513];
    __shared__ float encL[512];
    __shared__ float mv[512];
    __shared__ float wL[64];
    __shared__ float red[512];
    int b = blockIdx.x, tid = threadIdx.x;
    {
        const float* fp = feat_b + ((size_t)b * 512 + tid) * 100;
        float s = 0.f;
        for (int m = 0; m < 100; m += 4) {
            float4 v = *(const float4*)&fp[m];
            s += v.x + v.y + v.z + v.w;
        }
        float e = s * 0.01f;
        encL[tid] = e;
        red[tid] = e * e;
    }
    const float* ap = attm + (size_t)b * 32768;
    for (int i = tid; i < 32768; i += 512) attL[(i >> 9) * 513 + (i & 511)] = ap[i];
    __syncthreads();
    for (int o = 256; o; o >>= 1) {
        if (tid < o) red[tid] += red[tid + o];
        __syncthreads();
    }
    float escale = 1.f / fmaxf(sqrtf(red[0]), 1e-8f);
    if (tid < 64) {
        int n = tid;
        float ss = 0.f, dp = 0.f;
        for (int c = 0; c < 512; ++c) {
            float a = attL[n * 513 + c];
            ss = fmaf(a, a, ss);
            dp = fmaf(encL[c], a, dp);
        }
        float sc = dp * escale / fmaxf(sqrtf(ss), 1e-8f);
        float mx = sc;
#pragma unroll
        for (int o = 32; o; o >>= 1) mx = fmaxf(mx, __shfl_xor(mx, o));
        float e = expf(sc - mx);
        float seL = e;
#pragma unroll
        for (int o = 32; o; o >>= 1) seL += __shfl_xor(seL, o);
        wL[n] = e / seL;
    }
    __syncthreads();
    {
        int c = tid;
        float s = 0.f;
        for (int n = 0; n < 64; ++n) s = fmaf(wL[n], attL[n * 513 + c], s);
        mv[c] = s;
    }
    __syncthreads();
    for (int k = tid; k < 100; k += 512) {
        const float* wp = w_fc + (size_t)k * 1024;
        float acc = b_fc[k];
        for (int c = 0; c < 512; c += 4) {
            float4 w0 = *(const float4*)&wp[c];
            float4 w1 = *(const float4*)&wp[512 + c];
            acc = fmaf(encL[c], w0.x, acc);     acc = fmaf(encL[c + 1], w0.y, acc);
            acc = fmaf(encL[c + 2], w0.z, acc); acc = fmaf(encL[c + 3], w0.w, acc);
            acc = fmaf(mv[c], w1.x, acc);       acc = fmaf(mv[c + 1], w1.y, acc);
            acc = fmaf(mv[c + 2], w1.z, acc);   acc = fmaf(mv[c + 3], w1.w, acc);
        }
        out[b * 100 + k] = acc;
    }
}

extern "C" void kernel_launch(void* const* d_in, const int* in_sizes, int n_in,
                              void* d_out, int out_size, void* d_ws, size_t ws_size,
                              hipStream_t stream) {
    const float* feat_b = (const float*)d_in[0];
    const float* feat_m = (const float*)d_in[1];
    const float* w1x1   = (const float*)d_in[2];
    const float* gamma  = (const float*)d_in[3];
    const float* beta   = (const float*)d_in[4];
    const float* w1a    = (const float*)d_in[5];
    const float* w1b    = (const float*)d_in[6];
    const float* w2a    = (const float*)d_in[7];
    const float* w2b    = (const float*)d_in[8];
    const float* w_fc   = (const float*)d_in[9];
    const float* b_fc   = (const float*)d_in[10];

    float* ws    = (float*)d_ws;
    float* K1c   = ws;                     // 1296 (pad 1312)
    float* fbp   = ws + 1312;              // 51200
    float* fmp   = fbp + 51200;            // 409600
    float* corr  = fmp + 409600;           // 5120000
    float* g1    = corr + 5120000;         // 5120000
    float* attnm = g1 + 5120000;           // 51200
    float* attm  = attnm + 51200;          // 262144

    hipLaunchKernelGGL(k_proj2, dim3(72), dim3(512), 0, stream,
                       feat_b, feat_m, w1x1, gamma, beta, fbp, fmp);
    hipLaunchKernelGGL(k_corr, dim3(513), dim3(512), 0, stream,
                       fbp, fmp, w1a, w1b, K1c, corr);
    hipLaunchKernelGGL(k_cca, dim3(10, 512), dim3(64), 0, stream,
                       corr, K1c, w2a, g1);
    hipLaunchKernelGGL(k_msoft2, dim3(512), dim3(512), 0, stream, g1, w2b, attnm);
    hipLaunchKernelGGL(k_attmem, dim3(64, 4), dim3(128), 0, stream, attnm, feat_m, attm);
    hipLaunchKernelGGL(k_final, dim3(8), dim3(512), 0, stream,
                       feat_b, attm, w_fc, b_fc, (float*)d_out);
}

// Round 6
// 323.218 us; speedup vs baseline: 2.1265x; 1.0823x over previous
//
#include <hip/hip_runtime.h>
#include <hip/hip_bf16.h>

// ---------------------------------------------------------------------------
// CCAMemoryModel forward, f32 throughout.
//  k_proj2 : per-image tiled GEMM proj (mean-shift+BN+ReLU+L2norm)
//  k_corr  : per (b,n) 100x100x64 GEMM -> corr[bn][m][bpos]; block 512
//            composes Winograd-transformed K1w (block1 collapsed, F(2,3) on
//            the bw axis: 4 coeffs per (dm,dbh) tap per channel).
//  k_cca   : ONE WAVE per (bn, wm, mr-half) strip (grid 10x512x2).
//            Ring-prefetch 3 corr mcols/row; h-pass = Winograd F(2,3)
//            (4 accumulator banks, input transform shared across 16 ch);
//            g1 base-conv via in-wave shuffles. No barriers.
//  k_msoft2: fused g2 mem-conv (w2b) + gaussian-normalize + softmax over mem
//            + sum over base -> attn_memory.
//  k_attmem: att_mem[b,n,c]
//  k_final : enc (fused) + cosine weights + softmax + mem_vec + linear head
// ---------------------------------------------------------------------------

// One block per image (72 total: 8 feat_b + 64 feat_m).
__global__ __launch_bounds__(512) void k_proj2(const float* __restrict__ feat_b,
                                               const float* __restrict__ feat_m,
                                               const float* __restrict__ w1x1,
                                               const float* __restrict__ gamma,
                                               const float* __restrict__ beta,
                                               float* __restrict__ fbp,
                                               float* __restrict__ fmp) {
    __shared__ __align__(16) float xt[64][104];   // c-tile of x; reused as zbuf
    __shared__ __align__(16) float wt[64][68];    // c-tile of w1x1
    __shared__ float colsum[100];
    __shared__ float wsumL[64];
    __shared__ float invL[100];
    const int tid = threadIdx.x;
    const int img = blockIdx.x;
    const float* x;
    float* outp;
    if (img < 8) { x = feat_b + (size_t)img * 51200; outp = fbp + (size_t)img * 6400; }
    else         { x = feat_m + (size_t)(img - 8) * 51200; outp = fmp + (size_t)(img - 8) * 6400; }

    if (tid < 100) colsum[tid] = 0.f;
    if (tid < 64) wsumL[tid] = 0.f;
    const int r = tid >> 3, q = tid & 7;   // r: out-channel, q: hw-strip
    float acc[13];
#pragma unroll
    for (int j = 0; j < 13; ++j) acc[j] = 0.f;
    __syncthreads();

    for (int ct = 0; ct < 8; ++ct) {
        for (int i = tid; i < 1600; i += 512) {
            int row = i / 25, c4 = (i % 25) * 4;
            *(float4*)&xt[row][c4] = *(const float4*)&x[(size_t)(ct * 64 + row) * 100 + c4];
        }
        for (int i = tid; i < 1024; i += 512) {
            int row = i / 16, c4 = (i % 16) * 4;
            *(float4*)&wt[row][c4] = *(const float4*)&w1x1[(size_t)row * 512 + ct * 64 + c4];
        }
        __syncthreads();
        if (tid < 100) {
            float s = 0.f;
            for (int c = 0; c < 64; ++c) s += xt[c][tid];
            colsum[tid] += s;
        }
        if (tid < 64) {
            float s = 0.f;
            for (int c = 0; c < 64; ++c) s += wt[tid][c];
            wsumL[tid] += s;
        }
        for (int c = 0; c < 64; ++c) {
            float w = wt[r][c];
#pragma unroll
            for (int j = 0; j < 13; ++j) {
                int hw = q + 8 * j;
                if (hw < 100) acc[j] = fmaf(w, xt[c][hw], acc[j]);
            }
        }
        __syncthreads();
    }
    float g = gamma[r], be = beta[r], wsr = wsumL[r];
#pragma unroll
    for (int j = 0; j < 13; ++j) {
        int hw = q + 8 * j;
        if (hw < 100) {
            float mean = colsum[hw] * (1.f / 512.f);
            xt[r][hw] = fmaxf((acc[j] - mean * wsr) * g + be, 0.f);
        }
    }
    __syncthreads();
    if (tid < 100) {
        float ss = 0.f;
        for (int rr = 0; rr < 64; ++rr) { float z = xt[rr][tid]; ss = fmaf(z, z, ss); }
        invL[tid] = 1.f / fmaxf(sqrtf(ss), 1e-8f);
    }
    __syncthreads();
    for (int i = tid; i < 6400; i += 512) {
        int rr = i / 100, hw = i % 100;
        outp[i] = xt[rr][hw] * invL[hw];
    }
}

// Blocks 0..511: corr[bn][m][b] = sum_r fm[r][m]*fb[r][b].
// Block 512: Winograd filter transform of the composed block1 kernel:
//   K1w[(dm*3+dbh)*64 + j*16 + c], j=0..3:
//   g_dbw = sum_cp w1b[c,cp,dm]*w1a[cp,dbh*3+dbw];
//   j0=g0, j1=(g0+g1+g2)/2, j2=(g0-g1+g2)/2, j3=g2.
__global__ __launch_bounds__(512) void k_corr(const float* __restrict__ fbp,
                                              const float* __restrict__ fmp,
                                              const float* __restrict__ w1a,
                                              const float* __restrict__ w1b,
                                              float* __restrict__ K1w,
                                              float* __restrict__ corr) {
    if (blockIdx.x == 512) {
        for (int t = threadIdx.x; t < 432; t += 512) {
            int tap = t >> 4, c = t & 15;
            int dm = tap / 3, dbh = tap % 3;
            float g0 = 0.f, g1 = 0.f, g2 = 0.f;
            for (int cp = 0; cp < 16; ++cp) {
                float wb = w1b[(c * 16 + cp) * 9 + dm];
                g0 = fmaf(wb, w1a[cp * 9 + dbh * 3 + 0], g0);
                g1 = fmaf(wb, w1a[cp * 9 + dbh * 3 + 1], g1);
                g2 = fmaf(wb, w1a[cp * 9 + dbh * 3 + 2], g2);
            }
            int base = tap * 64 + c;
            K1w[base]      = g0;
            K1w[base + 16] = 0.5f * (g0 + g1 + g2);
            K1w[base + 32] = 0.5f * (g0 - g1 + g2);
            K1w[base + 48] = g2;
        }
        return;
    }
    __shared__ __align__(16) float A[6400];
    __shared__ __align__(16) float B[6400];
    const int tid = threadIdx.x, bn = blockIdx.x;
    const float* fm = fmp + (size_t)(bn & 63) * 6400;
    const float* fb = fbp + (size_t)(bn >> 6) * 6400;
    for (int i = tid * 4; i < 6400; i += 2048) {
        *(float4*)&A[i] = *(const float4*)&fm[i];
        *(float4*)&B[i] = *(const float4*)&fb[i];
    }
    __syncthreads();
    float* dst = corr + (size_t)bn * 10000;
    for (int u = tid; u < 625; u += 512) {
        int m0 = (u / 25) * 4, b0 = (u % 25) * 4;
        float acc[4][4] = {};
        for (int r = 0; r < 64; ++r) {
            float4 av = *(const float4*)&A[r * 100 + m0];
            float4 bv = *(const float4*)&B[r * 100 + b0];
            float a[4] = {av.x, av.y, av.z, av.w};
            float bb[4] = {bv.x, bv.y, bv.z, bv.w};
#pragma unroll
            for (int i = 0; i < 4; ++i)
#pragma unroll
                for (int j = 0; j < 4; ++j) acc[i][j] = fmaf(a[i], bb[j], acc[i][j]);
        }
#pragma unroll
        for (int i = 0; i < 4; ++i)
#pragma unroll
            for (int j = 0; j < 4; ++j) dst[(m0 + i) * 100 + (b0 + j)] = acc[i][j];
    }
}

// One wave per (wm, bn, half) strip. grid (10, 512, 2), block 64.
// half h: mr rows h*5 .. h*5+4.
// ring: 4 slots x [3 mcols][12 rows][14 cols] + zero slab. 2184 f32 = 8.7 KB.
__global__ __launch_bounds__(64, 4) void k_cca(const float* __restrict__ corr,
                                               const float* __restrict__ K1w,
                                               const float* __restrict__ w2a,
                                               float* __restrict__ g1out) {
    __shared__ float ring[2184];   // zero slab at 2016
    const int lane = threadIdx.x;
    const int wm = blockIdx.x, bn = blockIdx.y;
    const int mr_lo = blockIdx.z * 5, mr_hi = mr_lo + 4;
    const int R_max = (mr_hi + 1 < 9) ? mr_hi + 1 : 9;
    const int u = lane < 50 ? lane : 49;   // clamp spare lanes
    const int bh = u / 5, p = u % 5, bw0 = 2 * p;
    const bool act = lane < 50;

    for (int i = lane; i < 2184; i += 64) ring[i] = 0.f;
    const float* cbase = corr + (size_t)bn * 10000 + (wm - 1) * 100;
    const int i0 = (wm == 0) ? 100 : 0;
    const int i1 = (wm == 9) ? 200 : 300;

    auto prefetch = [&](int R) {
        if (R < 0 || R > R_max) return;
        const float* src = cbase + R * 1000;
        float* dslot = &ring[(R & 3) * 504];
#pragma unroll
        for (int k = 0; k < 5; ++k) {
            int i = lane + k * 64;
            if (i >= i0 && i < i1) {
                int mc = i / 100, t = i % 100;
                dslot[mc * 168 + (t / 10 + 1) * 14 + (t % 10 + 1)] = src[i];
            }
        }
    };
    prefetch(mr_lo - 1);
    prefetch(mr_lo);
    prefetch(mr_lo + 1);
    // single-wave block: DS ops are in-order per wave; no barrier needed.

    const int rbase = bh * 14 + bw0;
    for (int mr = mr_lo; mr <= mr_hi; ++mr) {
        prefetch(mr + 2);

        // ---- h pass: Winograd F(2,3) over bw, 4 accumulator banks ----
        float A1[16], A2[16], A3[16], A4[16];
#pragma unroll
        for (int c = 0; c < 16; ++c) { A1[c] = 0.f; A2[c] = 0.f; A3[c] = 0.f; A4[c] = 0.f; }
        for (int dmh = 0; dmh < 3; ++dmh) {
            int mrow = mr + dmh - 1;
            if ((unsigned)mrow >= 10u) continue;
            const float* slab0 = &ring[(mrow & 3) * 504];
#pragma unroll
            for (int dmw = 0; dmw < 3; ++dmw) {
                bool mv = (unsigned)(wm + dmw - 1) < 10u;
                const float* cb = (mv ? slab0 + dmw * 168 : &ring[2016]) + rbase;
                const float* kp = K1w + (dmh * 3 + dmw) * 192;
#pragma unroll
                for (int dbh = 0; dbh < 3; ++dbh) {
                    float2 lo = *(const float2*)&cb[dbh * 14];
                    float2 hi = *(const float2*)&cb[dbh * 14 + 2];
                    float t1 = lo.x - hi.x;
                    float t2 = lo.y + hi.x;
                    float t3 = hi.x - lo.y;
                    float t4 = lo.y - hi.y;
                    const float* kq = kp + dbh * 64;
#pragma unroll
                    for (int c = 0; c < 16; ++c) {
                        A1[c] = fmaf(t1, kq[c], A1[c]);
                        A2[c] = fmaf(t2, kq[16 + c], A2[c]);
                        A3[c] = fmaf(t3, kq[32 + c], A3[c]);
                        A4[c] = fmaf(t4, kq[48 + c], A4[c]);
                    }
                }
            }
        }

        // ---- g1 base-conv via in-wave shuffles (partial row sums) ----
        float P00 = 0.f, P01 = 0.f, P10 = 0.f, P11 = 0.f, P20 = 0.f, P21 = 0.f;
#pragma unroll
        for (int c = 0; c < 16; ++c) {
            float r0 = fmaxf(A1[c] + A2[c] + A3[c], 0.f);
            float r1 = fmaxf(A2[c] - A3[c] - A4[c], 0.f);
            float lA = __shfl(r1, lane - 1); lA = (p > 0) ? lA : 0.f;   // col bw0-1
            float rA = __shfl(r0, lane + 1); rA = (p < 4) ? rA : 0.f;   // col bw0+2
            const float* wq = w2a + c * 9;
            P00 = fmaf(wq[0], lA, fmaf(wq[1], r0, fmaf(wq[2], r1, P00)));
            P01 = fmaf(wq[0], r0, fmaf(wq[1], r1, fmaf(wq[2], rA, P01)));
            P10 = fmaf(wq[3], lA, fmaf(wq[4], r0, fmaf(wq[5], r1, P10)));
            P11 = fmaf(wq[3], r0, fmaf(wq[4], r1, fmaf(wq[5], rA, P11)));
            P20 = fmaf(wq[6], lA, fmaf(wq[7], r0, fmaf(wq[8], r1, P20)));
            P21 = fmaf(wq[6], r0, fmaf(wq[7], r1, fmaf(wq[8], rA, P21)));
        }
        // out row bh takes: P0 from row bh-1 (lane-5), own P1, P2 from row bh+1.
        float u00 = __shfl(P00, lane - 5), u01 = __shfl(P01, lane - 5);
        float u20 = __shfl(P20, lane + 5), u21 = __shfl(P21, lane + 5);
        if (bh == 0) { u00 = 0.f; u01 = 0.f; }
        if (bh == 9) { u20 = 0.f; u21 = 0.f; }
        float g0 = P10 + u00 + u20;
        float g1v = P11 + u01 + u21;
        if (act) {
            float2 st; st.x = g0; st.y = g1v;
            *(float2*)&g1out[(size_t)bn * 10000 + (mr * 10 + wm) * 100 + bh * 10 + bw0] = st;
        }
    }
}

// Fused g2 (w2b mem-conv) + gaussian-normalize over mem + softmax + sum over
// base. One block per bn (512 x 512 thr).
__global__ __launch_bounds__(512) void k_msoft2(const float* __restrict__ g1,
                                                const float* __restrict__ w2b,
                                                float* __restrict__ attnm) {
    __shared__ float gt[10000];
    const int tid = threadIdx.x, bn = blockIdx.x;
    const float* src = g1 + (size_t)bn * 10000;
    for (int i = tid; i < 10000; i += 512) gt[i] = src[i];
    __syncthreads();
    float wb[9];
#pragma unroll
    for (int t = 0; t < 9; ++t) wb[t] = w2b[t];
    const int b = tid >> 2, q = tid & 3;
    const bool act = tid < 400;
    float ev[25];
    float se = 0.f;
    if (act) {
        float s = 0.f, ss = 0.f;
#pragma unroll
        for (int i = 0; i < 25; ++i) {
            int m = q * 25 + i, mh = m / 10, mw = m % 10;
            float v = 0.f;
#pragma unroll
            for (int dh = 0; dh < 3; ++dh) {
                int rr = mh + dh - 1;
                if ((unsigned)rr < 10u) {
#pragma unroll
                    for (int dw = 0; dw < 3; ++dw) {
                        int ww = mw + dw - 1;
                        if ((unsigned)ww < 10u)
                            v = fmaf(wb[dh * 3 + dw], gt[(rr * 10 + ww) * 100 + b], v);
                    }
                }
            }
            ev[i] = v;
            s += v; ss = fmaf(v, v, ss);
        }
        s += __shfl_xor(s, 1); s += __shfl_xor(s, 2);
        ss += __shfl_xor(ss, 1); ss += __shfl_xor(ss, 2);
        float mean = s * 0.01f;
        float var = (ss - 100.f * mean * mean) * (1.f / 99.f);
        float istd = 0.2f / sqrtf(var + 1e-5f);  // includes 1/TEMP
        float mx = -1e30f;
#pragma unroll
        for (int i = 0; i < 25; ++i) mx = fmaxf(mx, ev[i]);
        mx = fmaxf(mx, __shfl_xor(mx, 1)); mx = fmaxf(mx, __shfl_xor(mx, 2));
#pragma unroll
        for (int i = 0; i < 25; ++i) {
            float e = expf((ev[i] - mx) * istd);
            ev[i] = e; se += e;
        }
        se += __shfl_xor(se, 1); se += __shfl_xor(se, 2);
    }
    __syncthreads();   // all conv reads of gt done
    if (act) {
        float inv = 1.f / se;
#pragma unroll
        for (int i = 0; i < 25; ++i) gt[(q * 25 + i) * 100 + b] = ev[i] * inv;
    }
    __syncthreads();
    if (act) {
        int m = tid >> 2;
        float s2 = 0.f;
#pragma unroll
        for (int i = 0; i < 25; ++i) s2 += gt[m * 100 + q * 25 + i];
        s2 += __shfl_xor(s2, 1); s2 += __shfl_xor(s2, 2);
        if (q == 0) attnm[bn * 100 + m] = s2;
    }
}

// grid (64 n, 4 c-chunks), block 128.
__global__ __launch_bounds__(128) void k_attmem(const float* __restrict__ attnm,
                                                const float* __restrict__ feat_m,
                                                float* __restrict__ attm) {
    __shared__ float A[8][100];
    int n = blockIdx.x, cq = blockIdx.y, tid = threadIdx.x;
    for (int i = tid; i < 800; i += 128) {
        int b = i / 100, m = i % 100;
        A[b][m] = attnm[(b * 64 + n) * 100 + m];
    }
    __syncthreads();
    int c = cq * 128 + tid;
    const float* fp = feat_m + ((size_t)n * 512 + c) * 100;
    float acc[8] = {};
    for (int m4 = 0; m4 < 100; m4 += 4) {
        float4 v = *(const float4*)&fp[m4];
#pragma unroll
        for (int b = 0; b < 8; ++b) {
            acc[b] = fmaf(A[b][m4], v.x, acc[b]);
            acc[b] = fmaf(A[b][m4 + 1], v.y, acc[b]);
            acc[b] = fmaf(A[b][m4 + 2], v.z, acc[b]);
            acc[b] = fmaf(A[b][m4 + 3], v.w, acc[b]);
        }
    }
#pragma unroll
    for (int b = 0; b < 8; ++b)
        attm[((size_t)(b * 64 + n)) * 512 + c] = acc[b] * 0.01f;
}

// Fused enc + memory-wrap head. One block per b (8 blocks, 512 threads).
__global__ __launch_bounds__(512) void k_final(const float* __restrict__ feat_b,
                                               const float* __restrict__ attm,
                                               const float* __restrict__ w_fc,
                                               const float* __restrict__ b_fc,
                                               float* __restrict__ out) {
    __shared__ float attL[64 * 513];
    __shared__ float encL[512];
    __shared__ float mv[512];
    __shared__ float wL[64];
    __shared__ float red[512];
    int b = blockIdx.x, tid = threadIdx.x;
    {
        const float* fp = feat_b + ((size_t)b * 512 + tid) * 100;
        float s = 0.f;
        for (int m = 0; m < 100; m += 4) {
            float4 v = *(const float4*)&fp[m];
            s += v.x + v.y + v.z + v.w;
        }
        float e = s * 0.01f;
        encL[tid] = e;
        red[tid] = e * e;
    }
    const float* ap = attm + (size_t)b * 32768;
    for (int i = tid; i < 32768; i += 512) attL[(i >> 9) * 513 + (i & 511)] = ap[i];
    __syncthreads();
    for (int o = 256; o; o >>= 1) {
        if (tid < o) red[tid] += red[tid + o];
        __syncthreads();
    }
    float escale = 1.f / fmaxf(sqrtf(red[0]), 1e-8f);
    if (tid < 64) {
        int n = tid;
        float ss = 0.f, dp = 0.f;
        for (int c = 0; c < 512; ++c) {
            float a = attL[n * 513 + c];
            ss = fmaf(a, a, ss);
            dp = fmaf(encL[c], a, dp);
        }
        float sc = dp * escale / fmaxf(sqrtf(ss), 1e-8f);
        float mx = sc;
#pragma unroll
        for (int o = 32; o; o >>= 1) mx = fmaxf(mx, __shfl_xor(mx, o));
        float e = expf(sc - mx);
        float seL = e;
#pragma unroll
        for (int o = 32; o; o >>= 1) seL += __shfl_xor(seL, o);
        wL[n] = e / seL;
    }
    __syncthreads();
    {
        int c = tid;
        float s = 0.f;
        for (int n = 0; n < 64; ++n) s = fmaf(wL[n], attL[n * 513 + c], s);
        mv[c] = s;
    }
    __syncthreads();
    for (int k = tid; k < 100; k += 512) {
        const float* wp = w_fc + (size_t)k * 1024;
        float acc = b_fc[k];
        for (int c = 0; c < 512; c += 4) {
            float4 w0 = *(const float4*)&wp[c];
            float4 w1 = *(const float4*)&wp[512 + c];
            acc = fmaf(encL[c], w0.x, acc);     acc = fmaf(encL[c + 1], w0.y, acc);
            acc = fmaf(encL[c + 2], w0.z, acc); acc = fmaf(encL[c + 3], w0.w, acc);
            acc = fmaf(mv[c], w1.x, acc);       acc = fmaf(mv[c + 1], w1.y, acc);
            acc = fmaf(mv[c + 2], w1.z, acc);   acc = fmaf(mv[c + 3], w1.w, acc);
        }
        out[b * 100 + k] = acc;
    }
}

extern "C" void kernel_launch(void* const* d_in, const int* in_sizes, int n_in,
                              void* d_out, int out_size, void* d_ws, size_t ws_size,
                              hipStream_t stream) {
    const float* feat_b = (const float*)d_in[0];
    const float* feat_m = (const float*)d_in[1];
    const float* w1x1   = (const float*)d_in[2];
    const float* gamma  = (const float*)d_in[3];
    const float* beta   = (const float*)d_in[4];
    const float* w1a    = (const float*)d_in[5];
    const float* w1b    = (const float*)d_in[6];
    const float* w2a    = (const float*)d_in[7];
    const float* w2b    = (const float*)d_in[8];
    const float* w_fc   = (const float*)d_in[9];
    const float* b_fc   = (const float*)d_in[10];

    float* ws    = (float*)d_ws;
    float* K1w   = ws;                     // 1728 (pad 1760)
    float* fbp   = ws + 1760;              // 51200
    float* fmp   = fbp + 51200;            // 409600
    float* corr  = fmp + 409600;           // 5120000
    float* g1    = corr + 5120000;         // 5120000
    float* attnm = g1 + 5120000;           // 51200
    float* attm  = attnm + 51200;          // 262144

    hipLaunchKernelGGL(k_proj2, dim3(72), dim3(512), 0, stream,
                       feat_b, feat_m, w1x1, gamma, beta, fbp, fmp);
    hipLaunchKernelGGL(k_corr, dim3(513), dim3(512), 0, stream,
                       fbp, fmp, w1a, w1b, K1w, corr);
    hipLaunchKernelGGL(k_cca, dim3(10, 512, 2), dim3(64), 0, stream,
                       corr, K1w, w2a, g1);
    hipLaunchKernelGGL(k_msoft2, dim3(512), dim3(512), 0, stream, g1, w2b, attnm);
    hipLaunchKernelGGL(k_attmem, dim3(64, 4), dim3(128), 0, stream, attnm, feat_m, attm);
    hipLaunchKernelGGL(k_final, dim3(8), dim3(512), 0, stream,
                       feat_b, attm, w_fc, b_fc, (float*)d_out);
}